// Round 6
// baseline (1692.118 us; speedup 1.0000x reference)
//
#include <hip/hip_runtime.h>
#include <math.h>

#define B 8
#define C 128
#define HEADS 8
#define HD 16
#define HH 128
#define WW 128
#define P 16384          // HH*WW

static __device__ __forceinline__ float PI2F() { return 6.28318530717958647692f; }

#define FMA2(ACC, W, X) \
    ACC.x = fmaf(W, X.x, ACC.x); ACC.y = fmaf(W, X.y, ACC.y);

// ===========================================================================
// Radix-2 DIT FFT-128 along the STRIDED (h) axis. 32 columns per block,
// 256 threads. GATE variant fuses sigmoid(W2*Mg+b2)*XF into staging.
template<int SIGN, bool GATE>
__global__ __launch_bounds__(256) void k_fftcol(
        const float* __restrict__ inR, const float* __restrict__ inI,
        const float* __restrict__ Mg, const float* __restrict__ w2,
        const float* __restrict__ b2,
        float* __restrict__ outR, float* __restrict__ outI) {
    __shared__ float2 S[128*32];
    __shared__ float2 tw[64];
    int bid = blockIdx.x;
    int img = bid >> 2;
    int qo  = (bid & 3) * 32;
    int tid = threadIdx.x;
    if (tid < 64) {
        float a = PI2F() * (float)tid / 128.0f;
        float s_, c_; __sincosf(a, &s_, &c_);
        tw[tid] = make_float2(c_, SIGN > 0 ? s_ : -s_);
    }
    long base = (long)img * P;
    float w2r[8]; float b2c = 0.f;
    const float* mb = nullptr;
    if (GATE) {
        int c = img & 127;
        #pragma unroll
        for (int j = 0; j < 8; ++j) w2r[j] = w2[c*8 + j];
        b2c = b2[c];
        mb = Mg + (long)(img >> 7)*8*P;
    }
    #pragma unroll
    for (int t = 0; t < 16; ++t) {
        int idx = tid + t*256;
        int h = idx >> 5, cc = idx & 31;
        int off = h*128 + qo + cc;
        float xr = inR[base + off];
        float xi = inI[base + off];
        if (GATE) {
            float z = b2c;
            #pragma unroll
            for (int j = 0; j < 8; ++j) z = fmaf(w2r[j], mb[(long)j*P + off], z);
            float g = 1.0f / (1.0f + __expf(-z));
            xr *= g; xi *= g;
        }
        int hr = __brev(h) >> 25;          // 7-bit reversal
        S[hr*32 + cc] = make_float2(xr, xi);
    }
    __syncthreads();
    int ln = tid & 31, wid = tid >> 5;
    for (int s = 0; s < 7; ++s) {
        int half = 1 << s;
        #pragma unroll
        for (int q = 0; q < 8; ++q) {
            int j = wid*8 + q;
            int k = j & (half - 1);
            int g = j >> s;
            int i0 = (g << (s+1)) + k;
            int i1 = i0 + half;
            float2 u = S[i0*32 + ln];
            float2 v = S[i1*32 + ln];
            float2 w = tw[k << (6 - s)];
            float vr = v.x*w.x - v.y*w.y;
            float vi = v.x*w.y + v.y*w.x;
            S[i0*32 + ln] = make_float2(u.x + vr, u.y + vi);
            S[i1*32 + ln] = make_float2(u.x - vr, u.y - vi);
        }
        __syncthreads();
    }
    #pragma unroll
    for (int t = 0; t < 16; ++t) {
        int idx = tid + t*256;
        int k = idx >> 5, cc = idx & 31;
        float2 z = S[k*32 + cc];
        outR[base + k*128 + qo + cc] = z.x;
        outI[base + k*128 + qo + cc] = z.y;
    }
}

// ===========================================================================
// Radix-2 DIT FFT-128 along the CONTIGUOUS (w) axis. 4 rows/block, 256 thr.
// MODE 0: real fwd; MODE 1: inverse+abs/16384; MODE 2: CT pass2 (premul
// twiddle, inverse, abs, transposed float4 store).
template<int MODE>
__global__ __launch_bounds__(256) void k_fftrow(
        const float* __restrict__ inR, const float* __restrict__ inI,
        float* __restrict__ out, float* __restrict__ outI) {
    __shared__ float2 S[4*128];
    __shared__ float2 tw[64];
    int bid = blockIdx.x;
    int img = bid >> 5;
    int r0  = (bid & 31) * 4;
    int tid = threadIdx.x;
    if (tid < 64) {
        float a = PI2F() * (float)tid / 128.0f;
        float s_, c_; __sincosf(a, &s_, &c_);
        tw[tid] = make_float2(c_, MODE == 0 ? -s_ : s_);
    }
    long base = (long)img * P;
    #pragma unroll
    for (int t = 0; t < 2; ++t) {
        int idx = tid + t*256;
        int r = idx >> 7, w = idx & 127;
        long off = base + (long)(r0 + r)*128 + w;
        float xr = inR[off];
        float xi = (MODE == 0) ? 0.f : inI[off];
        if (MODE == 2) {
            int k2 = r0 + r;
            float ang = (PI2F()/16384.0f) * (float)(w * k2);
            float s_, c_; __sincosf(ang, &s_, &c_);
            float yr = xr*c_ - xi*s_;
            float yi = xr*s_ + xi*c_;
            xr = yr; xi = yi;
        }
        S[r*128 + (__brev(w) >> 25)] = make_float2(xr, xi);
    }
    __syncthreads();
    int r = tid >> 6, j = tid & 63;
    for (int s = 0; s < 7; ++s) {
        int half = 1 << s;
        int k = j & (half - 1);
        int g = j >> s;
        int i0 = (g << (s+1)) + k;
        int i1 = i0 + half;
        float2 u = S[r*128 + i0];
        float2 v = S[r*128 + i1];
        float2 w_ = tw[k << (6 - s)];
        float vr = v.x*w_.x - v.y*w_.y;
        float vi = v.x*w_.y + v.y*w_.x;
        S[r*128 + i0] = make_float2(u.x + vr, u.y + vi);
        S[r*128 + i1] = make_float2(u.x - vr, u.y - vi);
        __syncthreads();
    }
    if (MODE == 0) {
        #pragma unroll
        for (int t = 0; t < 2; ++t) {
            int idx = tid + t*256;
            int rr = idx >> 7, k = idx & 127;
            float2 z = S[rr*128 + k];
            long off = base + (long)(r0 + rr)*128 + k;
            out[off] = z.x; outI[off] = z.y;
        }
    } else if (MODE == 1) {
        #pragma unroll
        for (int t = 0; t < 2; ++t) {
            int idx = tid + t*256;
            int rr = idx >> 7, p = idx & 127;
            float2 z = S[rr*128 + p];
            out[base + (long)(r0 + rr)*128 + p] =
                sqrtf(z.x*z.x + z.y*z.y) * (1.0f/16384.0f);
        }
    } else {
        if (tid < 128) {
            int k1 = tid;
            float4 v;
            float2 z0 = S[0*128 + k1], z1 = S[1*128 + k1];
            float2 z2 = S[2*128 + k1], z3 = S[3*128 + k1];
            v.x = sqrtf(z0.x*z0.x + z0.y*z0.y) * (1.0f/16384.0f);
            v.y = sqrtf(z1.x*z1.x + z1.y*z1.y) * (1.0f/16384.0f);
            v.z = sqrtf(z2.x*z2.x + z2.y*z2.y) * (1.0f/16384.0f);
            v.w = sqrtf(z3.x*z3.x + z3.y*z3.y) * (1.0f/16384.0f);
            *(float4*)(out + base + (long)k1*128 + r0) = v;
        }
    }
}

// ---------------------------------------------------------------------------
// Weight pre-transpose (runs once): qkv -> [g8][c][24], projf/projs -> [og][c][32]
__global__ __launch_bounds__(256) void k_prep_w(
        const float* __restrict__ q1w, const float* __restrict__ k1w,
        const float* __restrict__ v1w, const float* __restrict__ projf,
        const float* __restrict__ projs,
        float* __restrict__ Wqkv, float* __restrict__ Wpf, float* __restrict__ Wps) {
    int tid = threadIdx.x + blockIdx.x*256;
    if (tid < 16*128*24) {
        int g8 = tid / (128*24); int r = tid % (128*24);
        int c = r / 24; int j = r % 24;
        const float* W = (j < 8) ? q1w : (j < 16) ? k1w : v1w;
        int jj = j & 7;
        Wqkv[tid] = W[(g8*8 + jj)*128 + c];
    }
    int t2 = tid - 16*128*24;
    if (t2 >= 0 && t2 < 4*256*32) {
        int og = t2 / (256*32); int r = t2 % (256*32);
        int c = r / 32; int j = r % 32;
        Wpf[t2] = projf[(og*32 + j)*256 + c];
        Wps[t2] = projs[(og*32 + j)*256 + c];
    }
}

// ---------------------------------------------------------------------------
// SE gate stage 1. 256 blocks (full CU coverage), float2 px, register
// prefetch, transposed weights in LDS (float4 broadcast reads).
__global__ __launch_bounds__(256) void k_gate_mid(
        const float* __restrict__ XFr, const float* __restrict__ w1,
        const float* __restrict__ b1, const float* __restrict__ gamma,
        const float* __restrict__ beta, const float* __restrict__ mean,
        const float* __restrict__ var, float* __restrict__ M) {
    __shared__ float Wt[128][8];
    int tid = threadIdx.x;
    for (int i = tid; i < 1024; i += 256) { int c = i >> 3, j = i & 7; Wt[c][j] = w1[j*128 + c]; }
    __syncthreads();
    int tile = blockIdx.x;             // NB*32
    int b = tile >> 5;
    long pbase = (long)(tile & 31)*512 + tid*2;
    const float2* xp = (const float2*)(XFr + (long)b*C*P + pbase);
    float2 acc[8];
    #pragma unroll
    for (int j = 0; j < 8; ++j) { float bj = b1[j]; acc[j] = make_float2(bj, bj); }
    float2 xv = xp[0];
    for (int c = 0; c < 128; ++c) {
        float2 xn = xp[(c < 127 ? c + 1 : 127)*(P/2)];
        const float4* wp = (const float4*)(&Wt[c][0]);
        float4 w0 = wp[0], w1_ = wp[1];
        acc[0].x = fmaf(w0.x, xv.x, acc[0].x); acc[0].y = fmaf(w0.x, xv.y, acc[0].y);
        acc[1].x = fmaf(w0.y, xv.x, acc[1].x); acc[1].y = fmaf(w0.y, xv.y, acc[1].y);
        acc[2].x = fmaf(w0.z, xv.x, acc[2].x); acc[2].y = fmaf(w0.z, xv.y, acc[2].y);
        acc[3].x = fmaf(w0.w, xv.x, acc[3].x); acc[3].y = fmaf(w0.w, xv.y, acc[3].y);
        acc[4].x = fmaf(w1_.x, xv.x, acc[4].x); acc[4].y = fmaf(w1_.x, xv.y, acc[4].y);
        acc[5].x = fmaf(w1_.y, xv.x, acc[5].x); acc[5].y = fmaf(w1_.y, xv.y, acc[5].y);
        acc[6].x = fmaf(w1_.z, xv.x, acc[6].x); acc[6].y = fmaf(w1_.z, xv.y, acc[6].y);
        acc[7].x = fmaf(w1_.w, xv.x, acc[7].x); acc[7].y = fmaf(w1_.w, xv.y, acc[7].y);
        xv = xn;
    }
    #pragma unroll
    for (int j = 0; j < 8; ++j) {
        float sc = rsqrtf(var[j] + 1e-5f) * gamma[j];
        float sh = beta[j] - mean[j]*sc;
        float2 v;
        v.x = fmaxf(fmaf(acc[j].x, sc, sh), 0.f);
        v.y = fmaxf(fmaf(acc[j].y, sc, sh), 0.f);
        *(float2*)(M + ((long)b*8 + j)*P + pbase) = v;
    }
}

// ---------------------------------------------------------------------------
// Complex Gram, REAL part only, LDS-tiled with fused row-norm partials.
__global__ __launch_bounds__(256) void k_gram_cr(
        const float* __restrict__ Xr, const float* __restrict__ Xi,
        float* __restrict__ gramP, float* __restrict__ normP) {
    __shared__ float Sr[16][260];
    __shared__ float Si[16][260];
    int bh = blockIdx.x >> 3, ck = blockIdx.x & 7;
    int tid = threadIdx.x;
    int tile = tid & 15;        // 4x4 tile id: ci = tile>>2, di = tile&3
    int slice = tid >> 4;       // n-slice 0..15
    int ci4 = (tile >> 2) * 4, di4 = (tile & 3) * 4;
    long rowb = (long)bh * 16;
    int n0 = ck * 2048;
    float acc[4][4];
    #pragma unroll
    for (int a = 0; a < 4; ++a)
        #pragma unroll
        for (int b2 = 0; b2 < 4; ++b2) acc[a][b2] = 0.f;
    float nacc = 0.f;
    int nrow = tid & 15;             // row for norm phase
    int ngrp = tid >> 4;             // 16 cols per group
    for (int sc = 0; sc < 8; ++sc) {
        int nb = n0 + sc*256;
        if (sc) __syncthreads();
        for (int i = tid; i < 1024; i += 256) {
            int r = i >> 6, col = (i & 63) * 4;
            *(float4*)(&Sr[r][col]) = *(const float4*)(Xr + (rowb + r)*P + nb + col);
            *(float4*)(&Si[r][col]) = *(const float4*)(Xi + (rowb + r)*P + nb + col);
        }
        __syncthreads();
        #pragma unroll
        for (int it0 = 0; it0 < 4; ++it0) {
            int it = (it0 + slice) & 3;          // rotation: slices hit distinct banks
            int n = slice*16 + it*4;
            float4 cr[4], cii[4], dr[4], dii[4];
            #pragma unroll
            for (int a = 0; a < 4; ++a) {
                cr[a]  = *(const float4*)(&Sr[ci4 + a][n]);
                cii[a] = *(const float4*)(&Si[ci4 + a][n]);
                dr[a]  = *(const float4*)(&Sr[di4 + a][n]);
                dii[a] = *(const float4*)(&Si[di4 + a][n]);
            }
            #pragma unroll
            for (int a = 0; a < 4; ++a)
                #pragma unroll
                for (int b2 = 0; b2 < 4; ++b2) {
                    float t = acc[a][b2];
                    t = fmaf(cr[a].x, dr[b2].x, fmaf(-cii[a].x, dii[b2].x, t));
                    t = fmaf(cr[a].y, dr[b2].y, fmaf(-cii[a].y, dii[b2].y, t));
                    t = fmaf(cr[a].z, dr[b2].z, fmaf(-cii[a].z, dii[b2].z, t));
                    t = fmaf(cr[a].w, dr[b2].w, fmaf(-cii[a].w, dii[b2].w, t));
                    acc[a][b2] = t;
                }
        }
        #pragma unroll
        for (int it0 = 0; it0 < 4; ++it0) {
            int it = (it0 + ngrp) & 3;
            int n = ngrp*16 + it*4;
            float4 r4 = *(const float4*)(&Sr[nrow][n]);
            float4 i4 = *(const float4*)(&Si[nrow][n]);
            nacc = fmaf(r4.x, r4.x, fmaf(i4.x, i4.x, nacc));
            nacc = fmaf(r4.y, r4.y, fmaf(i4.y, i4.y, nacc));
            nacc = fmaf(r4.z, r4.z, fmaf(i4.z, i4.z, nacc));
            nacc = fmaf(r4.w, r4.w, fmaf(i4.w, i4.w, nacc));
        }
    }
    __syncthreads();
    float* red  = &Sr[0][0];     // 16 tiles * 16 slices * 16 locals = 4096 floats
    float* redn = &Si[0][0];     // 16 rows * 16 groups
    #pragma unroll
    for (int a = 0; a < 4; ++a)
        #pragma unroll
        for (int b2 = 0; b2 < 4; ++b2)
            red[tile*256 + slice*16 + a*4 + b2] = acc[a][b2];
    redn[nrow*16 + ngrp] = nacc;
    __syncthreads();
    {
        int c = tid >> 4, d = tid & 15;
        int tI = (c >> 2)*4 + (d >> 2);
        int lo = (c & 3)*4 + (d & 3);
        float g = 0.f;
        #pragma unroll
        for (int s = 0; s < 16; ++s) g += red[tI*256 + s*16 + lo];
        gramP[(long)(bh*8 + ck)*256 + tid] = g;
    }
    if (tid < 16) {
        float s = 0.f;
        #pragma unroll
        for (int k = 0; k < 16; ++k) s += redn[tid*16 + k];
        normP[(long)(bh*8 + ck)*16 + tid] = s;
    }
}

// ---------------------------------------------------------------------------
// Real Gram, LDS-tiled, fused norm partials for BOTH Q (c-side) and K (d-side).
__global__ __launch_bounds__(256) void k_gram_r(
        const float* __restrict__ Q, const float* __restrict__ K,
        float* __restrict__ gramP, float* __restrict__ qnormP,
        float* __restrict__ knormP) {
    __shared__ float Sq[16][260];
    __shared__ float Sk[16][260];
    int bh = blockIdx.x >> 3, ck = blockIdx.x & 7;
    int tid = threadIdx.x;
    int tile = tid & 15;
    int slice = tid >> 4;
    int ci4 = (tile >> 2) * 4, di4 = (tile & 3) * 4;
    long rowb = (long)bh * 16;
    int n0 = ck * 2048;
    float acc[4][4];
    #pragma unroll
    for (int a = 0; a < 4; ++a)
        #pragma unroll
        for (int b2 = 0; b2 < 4; ++b2) acc[a][b2] = 0.f;
    float qacc = 0.f, kacc = 0.f;
    int nrow = tid & 15, ngrp = tid >> 4;
    for (int sc = 0; sc < 8; ++sc) {
        int nb = n0 + sc*256;
        if (sc) __syncthreads();
        for (int i = tid; i < 1024; i += 256) {
            int r = i >> 6, col = (i & 63) * 4;
            *(float4*)(&Sq[r][col]) = *(const float4*)(Q + (rowb + r)*P + nb + col);
            *(float4*)(&Sk[r][col]) = *(const float4*)(K + (rowb + r)*P + nb + col);
        }
        __syncthreads();
        #pragma unroll
        for (int it0 = 0; it0 < 4; ++it0) {
            int it = (it0 + slice) & 3;
            int n = slice*16 + it*4;
            float4 cq[4], dk[4];
            #pragma unroll
            for (int a = 0; a < 4; ++a) {
                cq[a] = *(const float4*)(&Sq[ci4 + a][n]);
                dk[a] = *(const float4*)(&Sk[di4 + a][n]);
            }
            #pragma unroll
            for (int a = 0; a < 4; ++a)
                #pragma unroll
                for (int b2 = 0; b2 < 4; ++b2) {
                    float t = acc[a][b2];
                    t = fmaf(cq[a].x, dk[b2].x, t);
                    t = fmaf(cq[a].y, dk[b2].y, t);
                    t = fmaf(cq[a].z, dk[b2].z, t);
                    t = fmaf(cq[a].w, dk[b2].w, t);
                    acc[a][b2] = t;
                }
        }
        #pragma unroll
        for (int it0 = 0; it0 < 4; ++it0) {
            int it = (it0 + ngrp) & 3;
            int n = ngrp*16 + it*4;
            float4 q4 = *(const float4*)(&Sq[nrow][n]);
            float4 k4 = *(const float4*)(&Sk[nrow][n]);
            qacc = fmaf(q4.x, q4.x, qacc); kacc = fmaf(k4.x, k4.x, kacc);
            qacc = fmaf(q4.y, q4.y, qacc); kacc = fmaf(k4.y, k4.y, kacc);
            qacc = fmaf(q4.z, q4.z, qacc); kacc = fmaf(k4.z, k4.z, kacc);
            qacc = fmaf(q4.w, q4.w, qacc); kacc = fmaf(k4.w, k4.w, kacc);
        }
    }
    __syncthreads();
    float* red  = &Sq[0][0];
    float* redn = &Sk[0][0];     // [0..255] = q partials, [256..511] = k partials
    #pragma unroll
    for (int a = 0; a < 4; ++a)
        #pragma unroll
        for (int b2 = 0; b2 < 4; ++b2)
            red[tile*256 + slice*16 + a*4 + b2] = acc[a][b2];
    redn[nrow*16 + ngrp] = qacc;
    redn[256 + nrow*16 + ngrp] = kacc;
    __syncthreads();
    {
        int c = tid >> 4, d = tid & 15;
        int tI = (c >> 2)*4 + (d >> 2);
        int lo = (c & 3)*4 + (d & 3);
        float g = 0.f;
        #pragma unroll
        for (int s = 0; s < 16; ++s) g += red[tI*256 + s*16 + lo];
        gramP[(long)(bh*8 + ck)*256 + tid] = g;
    }
    if (tid < 16) {
        float s = 0.f;
        #pragma unroll
        for (int k = 0; k < 16; ++k) s += redn[tid*16 + k];
        qnormP[(long)(bh*8 + ck)*16 + tid] = s;
    } else if (tid < 32) {
        int r = tid - 16;
        float s = 0.f;
        #pragma unroll
        for (int k = 0; k < 16; ++k) s += redn[256 + r*16 + k];
        knormP[(long)(bh*8 + ck)*16 + r] = s;
    }
}

// ---------------------------------------------------------------------------
// attn_f: real gram -> softmax; imag part exactly uniform 1/16; IDFT-16 over c.
__global__ void k_attn_f(const float* __restrict__ gramP, const float* __restrict__ normP,
                         const float* __restrict__ tempf, float* __restrict__ attn2) {
    int bh = blockIdx.x; int tid = threadIdx.x;
    int c = tid >> 4, d = tid & 15;
    int hh = bh & 7;
    __shared__ float sR[256];
    __shared__ float2 t16[16];
    __shared__ float sN[16];
    if (tid < 16) {
        float s = 0.f;
        #pragma unroll
        for (int ck = 0; ck < 8; ++ck) s += normP[(long)(bh*8+ck)*16 + tid];
        sN[tid] = 1.0f / fmaxf(sqrtf(s), 1e-12f);
        float a = PI2F() * (float)tid / 16.0f;
        t16[tid] = make_float2(__cosf(a), __sinf(a));
    }
    float gr = 0.f;
    for (int ck = 0; ck < 8; ++ck) gr += gramP[(long)(bh*8+ck)*256 + tid];
    __syncthreads();
    float vr = gr * sN[c] * sN[d] * tempf[hh];
    float mr = vr;
    for (int off = 8; off >= 1; off >>= 1) mr = fmaxf(mr, __shfl_xor(mr, off));
    float er = __expf(vr - mr);
    float ssr = er;
    for (int off = 8; off >= 1; off >>= 1) ssr += __shfl_xor(ssr, off);
    float arv = er / ssr;
    const float u = 1.0f/16.0f;
    sR[tid] = arv;
    __syncthreads();
    float ar2 = 0.f, ai2 = 0.f;
    #pragma unroll
    for (int cc = 0; cc < 16; ++cc) {
        float2 t = t16[(cc*c) & 15];
        float xr = sR[cc*16 + d];
        ar2 = fmaf(xr, t.x, fmaf(-u, t.y, ar2));
        ai2 = fmaf(xr, t.y, fmaf( u, t.x, ai2));
    }
    long o = ((long)bh*256 + tid)*2;
    attn2[o]   = ar2 * (1.0f/16.0f);
    attn2[o+1] = ai2 * (1.0f/16.0f);
}

// ---------------------------------------------------------------------------
// Y[c][n] = sum_d attn2[c][d] * qf[d][n]   (complex)
__global__ void k_yf(const float* __restrict__ attn2, const float* __restrict__ Xr,
                     const float* __restrict__ Xi, float* __restrict__ Yr,
                     float* __restrict__ Yi) {
    int bh = blockIdx.x >> 6;
    int nb = blockIdx.x & 63;
    int tid = threadIdx.x;
    __shared__ float aR[256], aI[256];
    { long o = ((long)bh*256 + tid)*2; aR[tid] = attn2[o]; aI[tid] = attn2[o+1]; }
    __syncthreads();
    long n = (long)nb*256 + tid;
    long rowb = (long)bh*16;
    float qr[16], qi[16];
    #pragma unroll
    for (int dd = 0; dd < 16; ++dd) {
        qr[dd] = Xr[(rowb+dd)*P + n];
        qi[dd] = Xi[(rowb+dd)*P + n];
    }
    for (int cc = 0; cc < 16; ++cc) {
        float ar = 0.f, ai = 0.f;
        #pragma unroll
        for (int dd = 0; dd < 16; ++dd) {
            float tr = aR[cc*16+dd], ti = aI[cc*16+dd];
            ar = fmaf(tr, qr[dd], fmaf(-ti, qi[dd], ar));
            ai = fmaf(tr, qi[dd], fmaf( ti, qr[dd], ai));
        }
        Yr[(rowb+cc)*P + n] = ar;
        Yi[(rowb+cc)*P + n] = ai;
    }
}

// ---------------------------------------------------------------------------
// Fused q/k/v 1x1 convs: weights pre-transposed to [g8][c][24] and read via
// WAVE-UNIFORM loads (scalar pipe / K$, zero LDS) — the LDS-broadcast variant
// was LDS-port-bound (per-CU port shared by 4 SIMDs; 157 us at VALUBusy 36%).
// Thread = 2 px, register prefetch of x.
__global__ __launch_bounds__(256) void k_conv1x1qkv(
        const float* __restrict__ x, const float* __restrict__ Wt,
        const float* __restrict__ bq, const float* __restrict__ bk,
        const float* __restrict__ bv,
        float* __restrict__ Oq, float* __restrict__ Ok,
        float* __restrict__ Ov) {
    int g8 = blockIdx.y;               // 0..15 (8 out-ch per output)
    int b = blockIdx.z;
    int tid = threadIdx.x;
    long pbase = (long)blockIdx.x*512 + tid*2;
    const float2* xp = (const float2*)(x + (long)b*C*P + pbase);
    const float4* wp = (const float4*)(Wt + (long)g8*128*24);   // uniform
    float2 aq[8], ak[8], av[8];
    #pragma unroll
    for (int j = 0; j < 8; ++j) {
        float v;
        v = bq[g8*8 + j]; aq[j] = make_float2(v, v);
        v = bk[g8*8 + j]; ak[j] = make_float2(v, v);
        v = bv[g8*8 + j]; av[j] = make_float2(v, v);
    }
    float2 xv = xp[0];
    for (int c = 0; c < 128; ++c) {
        float2 xn = xp[(c < 127 ? c + 1 : 127)*(P/2)];
        float4 wq0 = wp[c*6+0], wq1 = wp[c*6+1];
        float4 wk0 = wp[c*6+2], wk1 = wp[c*6+3];
        float4 wv0 = wp[c*6+4], wv1 = wp[c*6+5];
        FMA2(aq[0], wq0.x, xv) FMA2(aq[1], wq0.y, xv) FMA2(aq[2], wq0.z, xv) FMA2(aq[3], wq0.w, xv)
        FMA2(aq[4], wq1.x, xv) FMA2(aq[5], wq1.y, xv) FMA2(aq[6], wq1.z, xv) FMA2(aq[7], wq1.w, xv)
        FMA2(ak[0], wk0.x, xv) FMA2(ak[1], wk0.y, xv) FMA2(ak[2], wk0.z, xv) FMA2(ak[3], wk0.w, xv)
        FMA2(ak[4], wk1.x, xv) FMA2(ak[5], wk1.y, xv) FMA2(ak[6], wk1.z, xv) FMA2(ak[7], wk1.w, xv)
        FMA2(av[0], wv0.x, xv) FMA2(av[1], wv0.y, xv) FMA2(av[2], wv0.z, xv) FMA2(av[3], wv0.w, xv)
        FMA2(av[4], wv1.x, xv) FMA2(av[5], wv1.y, xv) FMA2(av[6], wv1.z, xv) FMA2(av[7], wv1.w, xv)
        xv = xn;
    }
    long ob = (long)b*C*P + (long)g8*8*P + pbase;
    #pragma unroll
    for (int j = 0; j < 8; ++j) {
        *(float2*)(Oq + ob + (long)j*P) = aq[j];
        *(float2*)(Ok + ob + (long)j*P) = ak[j];
        *(float2*)(Ov + ob + (long)j*P) = av[j];
    }
}

// ---------------------------------------------------------------------------
// Grouped conv, LDS-tiled; one block computes BOTH the 3x3 out-ch (g) and the
// 5x5 out-ch (64+g) from the shared 2-channel input tile. 16-row tiles.
__global__ __launch_bounds__(256) void k_gconv(
        const float* __restrict__ in, const float* __restrict__ w3,
        const float* __restrict__ w5, float* __restrict__ out) {
    __shared__ float S[2*20*132];
    __shared__ float ws3[18], ws5[50];
    int ht = blockIdx.x;       // 0..7
    int g  = blockIdx.y;       // 0..63
    int b  = blockIdx.z;
    int tid = threadIdx.x;
    int h0 = ht*16;
    const float* ib = in + ((long)b*C + 2*g)*P;
    if (tid < 18) ws3[tid] = w3[g*18 + tid];
    else if (tid < 68) ws5[tid-18] = w5[g*50 + tid - 18];
    for (int i = tid; i < 2*20*132; i += 256) {
        int ic = i / 2640, rem = i % 2640;
        int t = rem / 132, cc = rem % 132;
        int h = h0 - 2 + t, w = cc - 2;
        float v = 0.f;
        if (h >= 0 && h < 128 && w >= 0 && w < 128)
            v = ib[(long)ic*P + h*128 + w];
        S[i] = v;
    }
    __syncthreads();
    int w = tid & 127, rh = tid >> 7;
    int lr0 = rh*8;
    float acc3[8], acc5[8];
    #pragma unroll
    for (int r = 0; r < 8; ++r) { acc3[r] = 0.f; acc5[r] = 0.f; }
    #pragma unroll
    for (int ic = 0; ic < 2; ++ic) {
        const float* Sc = S + ic*2640;
        #pragma unroll
        for (int kx = 0; kx < 3; ++kx) {
            float col[10];
            #pragma unroll
            for (int i = 0; i < 10; ++i)
                col[i] = Sc[(lr0 + 1 + i)*132 + (w + 1 + kx)];
            #pragma unroll
            for (int ky = 0; ky < 3; ++ky) {
                float wv = ws3[ic*9 + ky*3 + kx];
                #pragma unroll
                for (int r = 0; r < 8; ++r)
                    acc3[r] = fmaf(wv, col[r + ky], acc3[r]);
            }
        }
        #pragma unroll
        for (int kx = 0; kx < 5; ++kx) {
            float col[12];
            #pragma unroll
            for (int i = 0; i < 12; ++i)
                col[i] = Sc[(lr0 + i)*132 + (w + kx)];
            #pragma unroll
            for (int ky = 0; ky < 5; ++ky) {
                float wv = ws5[ic*25 + ky*5 + kx];
                #pragma unroll
                for (int r = 0; r < 8; ++r)
                    acc5[r] = fmaf(wv, col[r + ky], acc5[r]);
            }
        }
    }
    long ob3 = ((long)b*C + g)*P;
    long ob5 = ((long)b*C + 64 + g)*P;
    #pragma unroll
    for (int r = 0; r < 8; ++r) {
        int h = h0 + lr0 + r;
        out[ob3 + h*128 + w] = acc3[r];
        out[ob5 + h*128 + w] = acc5[r];
    }
}

// ---------------------------------------------------------------------------
// attn_s: norm reciprocals from fused partials, then softmax.
__global__ void k_attn_s(const float* __restrict__ gramP, const float* __restrict__ qnormP,
                         const float* __restrict__ knormP, const float* __restrict__ temps,
                         float* __restrict__ attn) {
    int bh = blockIdx.x; int tid = threadIdx.x;
    int c = tid >> 4, d = tid & 15;
    __shared__ float sQ[16], sK[16];
    if (tid < 16) {
        float sq = 0.f, sk = 0.f;
        #pragma unroll
        for (int ck = 0; ck < 8; ++ck) {
            sq += qnormP[(long)(bh*8+ck)*16 + tid];
            sk += knormP[(long)(bh*8+ck)*16 + tid];
        }
        sQ[tid] = 1.0f / fmaxf(sqrtf(sq), 1e-12f);
        sK[tid] = 1.0f / fmaxf(sqrtf(sk), 1e-12f);
    }
    float g = 0.f;
    for (int ck = 0; ck < 8; ++ck) g += gramP[(long)(bh*8+ck)*256 + tid];
    __syncthreads();
    g *= sQ[c] * sK[d] * temps[bh & 7];
    float m = g;
    for (int off = 8; off >= 1; off >>= 1) m = fmaxf(m, __shfl_xor(m, off));
    float e = __expf(g - m);
    float s = e;
    for (int off = 8; off >= 1; off >>= 1) s += __shfl_xor(s, off);
    attn[(long)bh*256 + tid] = e / s;
}

__global__ void k_outs(const float* __restrict__ attn, const float* __restrict__ V,
                       float* __restrict__ out) {
    int bh = blockIdx.x >> 6, nb = blockIdx.x & 63;
    int tid = threadIdx.x;
    __shared__ float aS[256];
    aS[tid] = attn[(long)bh*256 + tid];
    __syncthreads();
    long n = (long)nb*256 + tid;
    long rowb = (long)bh*16;
    float vv[16];
    #pragma unroll
    for (int dd = 0; dd < 16; ++dd) vv[dd] = V[(rowb+dd)*P + n];
    for (int cc = 0; cc < 16; ++cc) {
        float a = 0.f;
        #pragma unroll
        for (int dd = 0; dd < 16; ++dd) a = fmaf(aS[cc*16+dd], vv[dd], a);
        out[(rowb+cc)*P + n] = a;
    }
}

// ---------------------------------------------------------------------------
// Projection with 2 stacked inputs. 32 out-ch per block, thread = 2 px,
// register prefetch of A/B; weights pre-transposed to [og][c][32] and read
// via WAVE-UNIFORM loads (scalar pipe / K$, zero LDS).
// out = W[:, :128]*A + W[:, 128:]*Bc (+out if ADD)
template<bool ADD>
__global__ __launch_bounds__(256) void k_proj2in(
        const float* __restrict__ A, const float* __restrict__ Bc,
        const float* __restrict__ Wt, float* __restrict__ out) {
    int og = blockIdx.y;               // 0..3
    int b = blockIdx.z;
    int tid = threadIdx.x;
    long pbase = (long)blockIdx.x*512 + tid*2;
    long xb = (long)b*C*P;
    const float2* Ap = (const float2*)(A + xb + pbase);
    const float2* Bp = (const float2*)(Bc + xb + pbase);
    const float4* wb = (const float4*)(Wt + (long)og*256*32);   // uniform
    float2 acc[32];
    #pragma unroll
    for (int j = 0; j < 32; ++j) acc[j] = make_float2(0.f, 0.f);
    float2 a = Ap[0], bb = Bp[0];
    for (int c = 0; c < 128; ++c) {
        int cn = (c < 127 ? c + 1 : 127);
        float2 an = Ap[cn*(P/2)];
        float2 bn = Bp[cn*(P/2)];
        const float4* w0p = wb + c*8;
        const float4* w1p = wb + (c + 128)*8;
        #pragma unroll
        for (int q = 0; q < 8; ++q) {
            float4 w0 = w0p[q], w1 = w1p[q];
            int j = q*4;
            acc[j+0].x = fmaf(w0.x, a.x, fmaf(w1.x, bb.x, acc[j+0].x));
            acc[j+0].y = fmaf(w0.x, a.y, fmaf(w1.x, bb.y, acc[j+0].y));
            acc[j+1].x = fmaf(w0.y, a.x, fmaf(w1.y, bb.x, acc[j+1].x));
            acc[j+1].y = fmaf(w0.y, a.y, fmaf(w1.y, bb.y, acc[j+1].y));
            acc[j+2].x = fmaf(w0.z, a.x, fmaf(w1.z, bb.x, acc[j+2].x));
            acc[j+2].y = fmaf(w0.z, a.y, fmaf(w1.z, bb.y, acc[j+2].y));
            acc[j+3].x = fmaf(w0.w, a.x, fmaf(w1.w, bb.x, acc[j+3].x));
            acc[j+3].y = fmaf(w0.w, a.y, fmaf(w1.w, bb.y, acc[j+3].y));
        }
        a = an; bb = bn;
    }
    float* op = out + xb + (long)og*32*P + pbase;
    #pragma unroll
    for (int j = 0; j < 32; ++j) {
        float2 v = acc[j];
        if (ADD) {
            float2 o = *(float2*)(op + (long)j*P);
            v.x += o.x; v.y += o.y;
        }
        *(float2*)(op + (long)j*P) = v;
    }
}

// ---------------------------------------------------------------------------
#define W_EXTRA (16*128*24 + 2*4*256*32)   // Wqkv + Wpf + Wps floats

static long ws_need_bytes(int bc) {
    long pb = (long)bc * C * P;
    long extras = (long)bc*8*P           // Mg
                + (long)bc*1024*3        // normP, qnormP, knormP (8bh*8ck*16)
                + (long)bc*8*8*256       // gramC (real)
                + (long)bc*8*256*2       // attn2
                + (long)bc*8*8*256       // gramS
                + (long)bc*8*256         // attnS
                + W_EXTRA;               // transposed weights
    return (5*pb + extras) * 4;
}

extern "C" void kernel_launch(void* const* d_in, const int* in_sizes, int n_in,
                              void* d_out, int out_size, void* d_ws, size_t ws_size,
                              hipStream_t stream) {
    const float* x      = (const float*)d_in[0];
    const float* temp_f = (const float*)d_in[1];
    const float* w1     = (const float*)d_in[2];
    const float* b1     = (const float*)d_in[3];
    const float* bng    = (const float*)d_in[4];
    const float* bnb    = (const float*)d_in[5];
    const float* bnm    = (const float*)d_in[6];
    const float* bnv    = (const float*)d_in[7];
    const float* w2     = (const float*)d_in[8];
    const float* b2     = (const float*)d_in[9];
    const float* projf  = (const float*)d_in[10];
    const float* temp_s = (const float*)d_in[11];
    const float* q1w = (const float*)d_in[12]; const float* q1b = (const float*)d_in[13];
    const float* k1w = (const float*)d_in[14]; const float* k1b = (const float*)d_in[15];
    const float* v1w = (const float*)d_in[16]; const float* v1b = (const float*)d_in[17];
    const float* q3w = (const float*)d_in[18]; const float* q5w = (const float*)d_in[19];
    const float* k3w = (const float*)d_in[20]; const float* k5w = (const float*)d_in[21];
    const float* v3w = (const float*)d_in[22]; const float* v5w = (const float*)d_in[23];
    const float* c3w = (const float*)d_in[24]; const float* c5w = (const float*)d_in[25];
    const float* projs  = (const float*)d_in[26];
    float* out = (float*)d_out;
    float* ws = (float*)d_ws;

    int bc = 1;
    if ((long)ws_size >= ws_need_bytes(8)) bc = 8;
    else if ((long)ws_size >= ws_need_bytes(4)) bc = 4;
    else if ((long)ws_size >= ws_need_bytes(2)) bc = 2;
    const int NB = bc;
    const long pb = (long)bc * C * P;

    float* t0 = ws + 0*pb;
    float* t1 = ws + 1*pb;
    float* t2 = ws + 2*pb;
    float* t3 = ws + 3*pb;
    float* t4 = ws + 4*pb;
    float* Mg    = ws + 5*pb;
    float* normF = Mg + (long)bc*8*P;       // bc*8bh*8ck*16 norm partials
    float* recQ  = normF + (long)bc*1024;
    float* recK  = recQ + (long)bc*1024;
    float* gramC = recK + (long)bc*1024;
    float* attn2 = gramC + (long)bc*8*8*256;
    float* gramS = attn2 + (long)bc*8*256*2;
    float* attnS = gramS + (long)bc*8*8*256;
    float* Wqkv  = attnS + (long)bc*8*256;
    float* Wpf   = Wqkv + 16*128*24;
    float* Wps   = Wpf + 4*256*32;

    // one-time weight transpose (scalar-load layouts)
    k_prep_w<<<320, 256, 0, stream>>>(q1w, k1w, v1w, projf, projs, Wqkv, Wpf, Wps);

    for (int ckk = 0; ckk < 8/bc; ++ckk) {
        const float* xc = x + (long)ckk * bc * C * P;
        float* outc = out + (long)ckk * bc * C * P;

        // ================= frequency branch =================
        k_fftrow<0><<<NB*C*32, 256, 0, stream>>>(xc, nullptr, t0, t1);      // rows fwd
        k_fftcol<-1,false><<<NB*C*4, 256, 0, stream>>>(t0, t1, nullptr, nullptr,
                                                       nullptr, t2, t3);    // XF=(t2,t3)
        k_gate_mid<<<NB*32, 256, 0, stream>>>(t2, w1, b1, bng, bnb, bnm, bnv, Mg);
        k_fftcol<1,true><<<NB*C*4, 256, 0, stream>>>(t2, t3, Mg, w2, b2,
                                                     t0, t1);               // gate h-IFFT
        k_fftrow<1><<<NB*C*32, 256, 0, stream>>>(t0, t1, t4, nullptr);      // OFL=t4
        k_gram_cr<<<NB*8*8, 256, 0, stream>>>(t2, t3, gramC, normF);        // gram+norm
        k_attn_f<<<NB*8, 256, 0, stream>>>(gramC, normF, temp_f, attn2);
        k_yf<<<NB*8*64, 256, 0, stream>>>(attn2, t2, t3, t0, t1);           // Y=(t0,t1)
        k_fftcol<1,false><<<NB*C*4, 256, 0, stream>>>(t0, t1, nullptr, nullptr,
                                                      nullptr, t2, t3);     // CT pass1
        k_fftrow<2><<<NB*C*32, 256, 0, stream>>>(t2, t3, t0, nullptr);      // OF=t0
        k_proj2in<false><<<dim3(32, 4, NB), 256, 0, stream>>>(t0, t4, Wpf, outc);

        // ================= spatial branch =================
        k_conv1x1qkv<<<dim3(32, 16, NB), 256, 0, stream>>>(xc, Wqkv, q1b, k1b, v1b,
                                                           t0, t1, t2);
        k_gconv<<<dim3(8, 64, NB), 256, 0, stream>>>(t0, q3w, q5w, t3);   // QS=t3
        k_gconv<<<dim3(8, 64, NB), 256, 0, stream>>>(t1, k3w, k5w, t4);   // KS=t4
        k_gconv<<<dim3(8, 64, NB), 256, 0, stream>>>(t2, v3w, v5w, t0);   // VS=t0
        k_gconv<<<dim3(8, 64, NB), 256, 0, stream>>>(xc, c3w, c5w, t1);   // OSL=t1
        k_gram_r<<<NB*8*8, 256, 0, stream>>>(t3, t4, gramS, recQ, recK);  // gram+norms
        k_attn_s<<<NB*8, 256, 0, stream>>>(gramS, recQ, recK, temp_s, attnS);
        k_outs<<<NB*8*64, 256, 0, stream>>>(attnS, t0, t2);         // OS=t2
        k_proj2in<true><<<dim3(32, 4, NB), 256, 0, stream>>>(t2, t1, Wps, outc);
    }
}

// Round 7
// 1488.064 us; speedup vs baseline: 1.1371x; 1.1371x over previous
//
#include <hip/hip_runtime.h>
#include <math.h>

#define B 8
#define C 128
#define HEADS 8
#define HD 16
#define HH 128
#define WW 128
#define P 16384          // HH*WW

static __device__ __forceinline__ float PI2F() { return 6.28318530717958647692f; }

#define FMA4(ACC, W, X) \
    ACC.x = fmaf(W, X.x, ACC.x); ACC.y = fmaf(W, X.y, ACC.y); \
    ACC.z = fmaf(W, X.z, ACC.z); ACC.w = fmaf(W, X.w, ACC.w);

// ===========================================================================
// Radix-2 DIT FFT-128 along the STRIDED (h) axis. 32 columns per block,
// 256 threads. GATE variant fuses sigmoid(W2*Mg+b2)*XF into staging.
template<int SIGN, bool GATE>
__global__ __launch_bounds__(256) void k_fftcol(
        const float* __restrict__ inR, const float* __restrict__ inI,
        const float* __restrict__ Mg, const float* __restrict__ w2,
        const float* __restrict__ b2,
        float* __restrict__ outR, float* __restrict__ outI) {
    __shared__ float2 S[128*32];
    __shared__ float2 tw[64];
    int bid = blockIdx.x;
    int img = bid >> 2;
    int qo  = (bid & 3) * 32;
    int tid = threadIdx.x;
    if (tid < 64) {
        float a = PI2F() * (float)tid / 128.0f;
        float s_, c_; __sincosf(a, &s_, &c_);
        tw[tid] = make_float2(c_, SIGN > 0 ? s_ : -s_);
    }
    long base = (long)img * P;
    float w2r[8]; float b2c = 0.f;
    const float* mb = nullptr;
    if (GATE) {
        int c = img & 127;
        #pragma unroll
        for (int j = 0; j < 8; ++j) w2r[j] = w2[c*8 + j];
        b2c = b2[c];
        mb = Mg + (long)(img >> 7)*8*P;
    }
    #pragma unroll
    for (int t = 0; t < 16; ++t) {
        int idx = tid + t*256;
        int h = idx >> 5, cc = idx & 31;
        int off = h*128 + qo + cc;
        float xr = inR[base + off];
        float xi = inI[base + off];
        if (GATE) {
            float z = b2c;
            #pragma unroll
            for (int j = 0; j < 8; ++j) z = fmaf(w2r[j], mb[(long)j*P + off], z);
            float g = 1.0f / (1.0f + __expf(-z));
            xr *= g; xi *= g;
        }
        int hr = __brev(h) >> 25;          // 7-bit reversal
        S[hr*32 + cc] = make_float2(xr, xi);
    }
    __syncthreads();
    int ln = tid & 31, wid = tid >> 5;
    for (int s = 0; s < 7; ++s) {
        int half = 1 << s;
        #pragma unroll
        for (int q = 0; q < 8; ++q) {
            int j = wid*8 + q;
            int k = j & (half - 1);
            int g = j >> s;
            int i0 = (g << (s+1)) + k;
            int i1 = i0 + half;
            float2 u = S[i0*32 + ln];
            float2 v = S[i1*32 + ln];
            float2 w = tw[k << (6 - s)];
            float vr = v.x*w.x - v.y*w.y;
            float vi = v.x*w.y + v.y*w.x;
            S[i0*32 + ln] = make_float2(u.x + vr, u.y + vi);
            S[i1*32 + ln] = make_float2(u.x - vr, u.y - vi);
        }
        __syncthreads();
    }
    #pragma unroll
    for (int t = 0; t < 16; ++t) {
        int idx = tid + t*256;
        int k = idx >> 5, cc = idx & 31;
        float2 z = S[k*32 + cc];
        outR[base + k*128 + qo + cc] = z.x;
        outI[base + k*128 + qo + cc] = z.y;
    }
}

// ===========================================================================
// Radix-2 DIT FFT-128 along the CONTIGUOUS (w) axis. 4 rows/block, 256 thr.
// MODE 0: real fwd; MODE 1: inverse+abs/16384; MODE 2: CT pass2 (premul
// twiddle, inverse, abs, transposed float4 store).
template<int MODE>
__global__ __launch_bounds__(256) void k_fftrow(
        const float* __restrict__ inR, const float* __restrict__ inI,
        float* __restrict__ out, float* __restrict__ outI) {
    __shared__ float2 S[4*128];
    __shared__ float2 tw[64];
    int bid = blockIdx.x;
    int img = bid >> 5;
    int r0  = (bid & 31) * 4;
    int tid = threadIdx.x;
    if (tid < 64) {
        float a = PI2F() * (float)tid / 128.0f;
        float s_, c_; __sincosf(a, &s_, &c_);
        tw[tid] = make_float2(c_, MODE == 0 ? -s_ : s_);
    }
    long base = (long)img * P;
    #pragma unroll
    for (int t = 0; t < 2; ++t) {
        int idx = tid + t*256;
        int r = idx >> 7, w = idx & 127;
        long off = base + (long)(r0 + r)*128 + w;
        float xr = inR[off];
        float xi = (MODE == 0) ? 0.f : inI[off];
        if (MODE == 2) {
            int k2 = r0 + r;
            float ang = (PI2F()/16384.0f) * (float)(w * k2);
            float s_, c_; __sincosf(ang, &s_, &c_);
            float yr = xr*c_ - xi*s_;
            float yi = xr*s_ + xi*c_;
            xr = yr; xi = yi;
        }
        S[r*128 + (__brev(w) >> 25)] = make_float2(xr, xi);
    }
    __syncthreads();
    int r = tid >> 6, j = tid & 63;
    for (int s = 0; s < 7; ++s) {
        int half = 1 << s;
        int k = j & (half - 1);
        int g = j >> s;
        int i0 = (g << (s+1)) + k;
        int i1 = i0 + half;
        float2 u = S[r*128 + i0];
        float2 v = S[r*128 + i1];
        float2 w_ = tw[k << (6 - s)];
        float vr = v.x*w_.x - v.y*w_.y;
        float vi = v.x*w_.y + v.y*w_.x;
        S[r*128 + i0] = make_float2(u.x + vr, u.y + vi);
        S[r*128 + i1] = make_float2(u.x - vr, u.y - vi);
        __syncthreads();
    }
    if (MODE == 0) {
        #pragma unroll
        for (int t = 0; t < 2; ++t) {
            int idx = tid + t*256;
            int rr = idx >> 7, k = idx & 127;
            float2 z = S[rr*128 + k];
            long off = base + (long)(r0 + rr)*128 + k;
            out[off] = z.x; outI[off] = z.y;
        }
    } else if (MODE == 1) {
        #pragma unroll
        for (int t = 0; t < 2; ++t) {
            int idx = tid + t*256;
            int rr = idx >> 7, p = idx & 127;
            float2 z = S[rr*128 + p];
            out[base + (long)(r0 + rr)*128 + p] =
                sqrtf(z.x*z.x + z.y*z.y) * (1.0f/16384.0f);
        }
    } else {
        if (tid < 128) {
            int k1 = tid;
            float4 v;
            float2 z0 = S[0*128 + k1], z1 = S[1*128 + k1];
            float2 z2 = S[2*128 + k1], z3 = S[3*128 + k1];
            v.x = sqrtf(z0.x*z0.x + z0.y*z0.y) * (1.0f/16384.0f);
            v.y = sqrtf(z1.x*z1.x + z1.y*z1.y) * (1.0f/16384.0f);
            v.z = sqrtf(z2.x*z2.x + z2.y*z2.y) * (1.0f/16384.0f);
            v.w = sqrtf(z3.x*z3.x + z3.y*z3.y) * (1.0f/16384.0f);
            *(float4*)(out + base + (long)k1*128 + r0) = v;
        }
    }
}

// ---------------------------------------------------------------------------
// SE gate stage 1. 256 blocks (full CU coverage), float2 px, register
// prefetch, transposed weights in LDS (float4 broadcast reads).
__global__ __launch_bounds__(256) void k_gate_mid(
        const float* __restrict__ XFr, const float* __restrict__ w1,
        const float* __restrict__ b1, const float* __restrict__ gamma,
        const float* __restrict__ beta, const float* __restrict__ mean,
        const float* __restrict__ var, float* __restrict__ M) {
    __shared__ float Wt[128][8];
    int tid = threadIdx.x;
    for (int i = tid; i < 1024; i += 256) { int c = i >> 3, j = i & 7; Wt[c][j] = w1[j*128 + c]; }
    __syncthreads();
    int tile = blockIdx.x;             // NB*32
    int b = tile >> 5;
    long pbase = (long)(tile & 31)*512 + tid*2;
    const float2* xp = (const float2*)(XFr + (long)b*C*P + pbase);
    float2 acc[8];
    #pragma unroll
    for (int j = 0; j < 8; ++j) { float bj = b1[j]; acc[j] = make_float2(bj, bj); }
    float2 xv = xp[0];
    for (int c = 0; c < 128; ++c) {
        float2 xn = xp[(c < 127 ? c + 1 : 127)*(P/2)];
        const float4* wp = (const float4*)(&Wt[c][0]);
        float4 w0 = wp[0], w1_ = wp[1];
        acc[0].x = fmaf(w0.x, xv.x, acc[0].x); acc[0].y = fmaf(w0.x, xv.y, acc[0].y);
        acc[1].x = fmaf(w0.y, xv.x, acc[1].x); acc[1].y = fmaf(w0.y, xv.y, acc[1].y);
        acc[2].x = fmaf(w0.z, xv.x, acc[2].x); acc[2].y = fmaf(w0.z, xv.y, acc[2].y);
        acc[3].x = fmaf(w0.w, xv.x, acc[3].x); acc[3].y = fmaf(w0.w, xv.y, acc[3].y);
        acc[4].x = fmaf(w1_.x, xv.x, acc[4].x); acc[4].y = fmaf(w1_.x, xv.y, acc[4].y);
        acc[5].x = fmaf(w1_.y, xv.x, acc[5].x); acc[5].y = fmaf(w1_.y, xv.y, acc[5].y);
        acc[6].x = fmaf(w1_.z, xv.x, acc[6].x); acc[6].y = fmaf(w1_.z, xv.y, acc[6].y);
        acc[7].x = fmaf(w1_.w, xv.x, acc[7].x); acc[7].y = fmaf(w1_.w, xv.y, acc[7].y);
        xv = xn;
    }
    #pragma unroll
    for (int j = 0; j < 8; ++j) {
        float sc = rsqrtf(var[j] + 1e-5f) * gamma[j];
        float sh = beta[j] - mean[j]*sc;
        float2 v;
        v.x = fmaxf(fmaf(acc[j].x, sc, sh), 0.f);
        v.y = fmaxf(fmaf(acc[j].y, sc, sh), 0.f);
        *(float2*)(M + ((long)b*8 + j)*P + pbase) = v;
    }
}

// ---------------------------------------------------------------------------
// Complex Gram, REAL part only, LDS-tiled with fused row-norm partials.
__global__ __launch_bounds__(256) void k_gram_cr(
        const float* __restrict__ Xr, const float* __restrict__ Xi,
        float* __restrict__ gramP, float* __restrict__ normP) {
    __shared__ float Sr[16][260];
    __shared__ float Si[16][260];
    int bh = blockIdx.x >> 3, ck = blockIdx.x & 7;
    int tid = threadIdx.x;
    int tile = tid & 15;        // 4x4 tile id: ci = tile>>2, di = tile&3
    int slice = tid >> 4;       // n-slice 0..15
    int ci4 = (tile >> 2) * 4, di4 = (tile & 3) * 4;
    long rowb = (long)bh * 16;
    int n0 = ck * 2048;
    float acc[4][4];
    #pragma unroll
    for (int a = 0; a < 4; ++a)
        #pragma unroll
        for (int b2 = 0; b2 < 4; ++b2) acc[a][b2] = 0.f;
    float nacc = 0.f;
    int nrow = tid & 15;             // row for norm phase
    int ngrp = tid >> 4;             // 16 cols per group
    for (int sc = 0; sc < 8; ++sc) {
        int nb = n0 + sc*256;
        if (sc) __syncthreads();
        for (int i = tid; i < 1024; i += 256) {
            int r = i >> 6, col = (i & 63) * 4;
            *(float4*)(&Sr[r][col]) = *(const float4*)(Xr + (rowb + r)*P + nb + col);
            *(float4*)(&Si[r][col]) = *(const float4*)(Xi + (rowb + r)*P + nb + col);
        }
        __syncthreads();
        #pragma unroll
        for (int it0 = 0; it0 < 4; ++it0) {
            int it = (it0 + slice) & 3;          // rotation: slices hit distinct banks
            int n = slice*16 + it*4;
            float4 cr[4], cii[4], dr[4], dii[4];
            #pragma unroll
            for (int a = 0; a < 4; ++a) {
                cr[a]  = *(const float4*)(&Sr[ci4 + a][n]);
                cii[a] = *(const float4*)(&Si[ci4 + a][n]);
                dr[a]  = *(const float4*)(&Sr[di4 + a][n]);
                dii[a] = *(const float4*)(&Si[di4 + a][n]);
            }
            #pragma unroll
            for (int a = 0; a < 4; ++a)
                #pragma unroll
                for (int b2 = 0; b2 < 4; ++b2) {
                    float t = acc[a][b2];
                    t = fmaf(cr[a].x, dr[b2].x, fmaf(-cii[a].x, dii[b2].x, t));
                    t = fmaf(cr[a].y, dr[b2].y, fmaf(-cii[a].y, dii[b2].y, t));
                    t = fmaf(cr[a].z, dr[b2].z, fmaf(-cii[a].z, dii[b2].z, t));
                    t = fmaf(cr[a].w, dr[b2].w, fmaf(-cii[a].w, dii[b2].w, t));
                    acc[a][b2] = t;
                }
        }
        #pragma unroll
        for (int it0 = 0; it0 < 4; ++it0) {
            int it = (it0 + ngrp) & 3;
            int n = ngrp*16 + it*4;
            float4 r4 = *(const float4*)(&Sr[nrow][n]);
            float4 i4 = *(const float4*)(&Si[nrow][n]);
            nacc = fmaf(r4.x, r4.x, fmaf(i4.x, i4.x, nacc));
            nacc = fmaf(r4.y, r4.y, fmaf(i4.y, i4.y, nacc));
            nacc = fmaf(r4.z, r4.z, fmaf(i4.z, i4.z, nacc));
            nacc = fmaf(r4.w, r4.w, fmaf(i4.w, i4.w, nacc));
        }
    }
    __syncthreads();
    float* red  = &Sr[0][0];     // 16 tiles * 16 slices * 16 locals = 4096 floats
    float* redn = &Si[0][0];     // 16 rows * 16 groups
    #pragma unroll
    for (int a = 0; a < 4; ++a)
        #pragma unroll
        for (int b2 = 0; b2 < 4; ++b2)
            red[tile*256 + slice*16 + a*4 + b2] = acc[a][b2];
    redn[nrow*16 + ngrp] = nacc;
    __syncthreads();
    {
        int c = tid >> 4, d = tid & 15;
        int tI = (c >> 2)*4 + (d >> 2);
        int lo = (c & 3)*4 + (d & 3);
        float g = 0.f;
        #pragma unroll
        for (int s = 0; s < 16; ++s) g += red[tI*256 + s*16 + lo];
        gramP[(long)(bh*8 + ck)*256 + tid] = g;
    }
    if (tid < 16) {
        float s = 0.f;
        #pragma unroll
        for (int k = 0; k < 16; ++k) s += redn[tid*16 + k];
        normP[(long)(bh*8 + ck)*16 + tid] = s;
    }
}

// ---------------------------------------------------------------------------
// Real Gram, LDS-tiled, fused norm partials for BOTH Q (c-side) and K (d-side).
__global__ __launch_bounds__(256) void k_gram_r(
        const float* __restrict__ Q, const float* __restrict__ K,
        float* __restrict__ gramP, float* __restrict__ qnormP,
        float* __restrict__ knormP) {
    __shared__ float Sq[16][260];
    __shared__ float Sk[16][260];
    int bh = blockIdx.x >> 3, ck = blockIdx.x & 7;
    int tid = threadIdx.x;
    int tile = tid & 15;
    int slice = tid >> 4;
    int ci4 = (tile >> 2) * 4, di4 = (tile & 3) * 4;
    long rowb = (long)bh * 16;
    int n0 = ck * 2048;
    float acc[4][4];
    #pragma unroll
    for (int a = 0; a < 4; ++a)
        #pragma unroll
        for (int b2 = 0; b2 < 4; ++b2) acc[a][b2] = 0.f;
    float qacc = 0.f, kacc = 0.f;
    int nrow = tid & 15, ngrp = tid >> 4;
    for (int sc = 0; sc < 8; ++sc) {
        int nb = n0 + sc*256;
        if (sc) __syncthreads();
        for (int i = tid; i < 1024; i += 256) {
            int r = i >> 6, col = (i & 63) * 4;
            *(float4*)(&Sq[r][col]) = *(const float4*)(Q + (rowb + r)*P + nb + col);
            *(float4*)(&Sk[r][col]) = *(const float4*)(K + (rowb + r)*P + nb + col);
        }
        __syncthreads();
        #pragma unroll
        for (int it0 = 0; it0 < 4; ++it0) {
            int it = (it0 + slice) & 3;
            int n = slice*16 + it*4;
            float4 cq[4], dk[4];
            #pragma unroll
            for (int a = 0; a < 4; ++a) {
                cq[a] = *(const float4*)(&Sq[ci4 + a][n]);
                dk[a] = *(const float4*)(&Sk[di4 + a][n]);
            }
            #pragma unroll
            for (int a = 0; a < 4; ++a)
                #pragma unroll
                for (int b2 = 0; b2 < 4; ++b2) {
                    float t = acc[a][b2];
                    t = fmaf(cq[a].x, dk[b2].x, t);
                    t = fmaf(cq[a].y, dk[b2].y, t);
                    t = fmaf(cq[a].z, dk[b2].z, t);
                    t = fmaf(cq[a].w, dk[b2].w, t);
                    acc[a][b2] = t;
                }
        }
        #pragma unroll
        for (int it0 = 0; it0 < 4; ++it0) {
            int it = (it0 + ngrp) & 3;
            int n = ngrp*16 + it*4;
            float4 q4 = *(const float4*)(&Sq[nrow][n]);
            float4 k4 = *(const float4*)(&Sk[nrow][n]);
            qacc = fmaf(q4.x, q4.x, qacc); kacc = fmaf(k4.x, k4.x, kacc);
            qacc = fmaf(q4.y, q4.y, qacc); kacc = fmaf(k4.y, k4.y, kacc);
            qacc = fmaf(q4.z, q4.z, qacc); kacc = fmaf(k4.z, k4.z, kacc);
            qacc = fmaf(q4.w, q4.w, qacc); kacc = fmaf(k4.w, k4.w, kacc);
        }
    }
    __syncthreads();
    float* red  = &Sq[0][0];
    float* redn = &Sk[0][0];     // [0..255] = q partials, [256..511] = k partials
    #pragma unroll
    for (int a = 0; a < 4; ++a)
        #pragma unroll
        for (int b2 = 0; b2 < 4; ++b2)
            red[tile*256 + slice*16 + a*4 + b2] = acc[a][b2];
    redn[nrow*16 + ngrp] = qacc;
    redn[256 + nrow*16 + ngrp] = kacc;
    __syncthreads();
    {
        int c = tid >> 4, d = tid & 15;
        int tI = (c >> 2)*4 + (d >> 2);
        int lo = (c & 3)*4 + (d & 3);
        float g = 0.f;
        #pragma unroll
        for (int s = 0; s < 16; ++s) g += red[tI*256 + s*16 + lo];
        gramP[(long)(bh*8 + ck)*256 + tid] = g;
    }
    if (tid < 16) {
        float s = 0.f;
        #pragma unroll
        for (int k = 0; k < 16; ++k) s += redn[tid*16 + k];
        qnormP[(long)(bh*8 + ck)*16 + tid] = s;
    } else if (tid < 32) {
        int r = tid - 16;
        float s = 0.f;
        #pragma unroll
        for (int k = 0; k < 16; ++k) s += redn[256 + r*16 + k];
        knormP[(long)(bh*8 + ck)*16 + r] = s;
    }
}

// ---------------------------------------------------------------------------
// attn_f: real gram -> softmax; imag part exactly uniform 1/16; IDFT-16 over c.
__global__ void k_attn_f(const float* __restrict__ gramP, const float* __restrict__ normP,
                         const float* __restrict__ tempf, float* __restrict__ attn2) {
    int bh = blockIdx.x; int tid = threadIdx.x;
    int c = tid >> 4, d = tid & 15;
    int hh = bh & 7;
    __shared__ float sR[256];
    __shared__ float2 t16[16];
    __shared__ float sN[16];
    if (tid < 16) {
        float s = 0.f;
        #pragma unroll
        for (int ck = 0; ck < 8; ++ck) s += normP[(long)(bh*8+ck)*16 + tid];
        sN[tid] = 1.0f / fmaxf(sqrtf(s), 1e-12f);
        float a = PI2F() * (float)tid / 16.0f;
        t16[tid] = make_float2(__cosf(a), __sinf(a));
    }
    float gr = 0.f;
    for (int ck = 0; ck < 8; ++ck) gr += gramP[(long)(bh*8+ck)*256 + tid];
    __syncthreads();
    float vr = gr * sN[c] * sN[d] * tempf[hh];
    float mr = vr;
    for (int off = 8; off >= 1; off >>= 1) mr = fmaxf(mr, __shfl_xor(mr, off));
    float er = __expf(vr - mr);
    float ssr = er;
    for (int off = 8; off >= 1; off >>= 1) ssr += __shfl_xor(ssr, off);
    float arv = er / ssr;
    const float u = 1.0f/16.0f;
    sR[tid] = arv;
    __syncthreads();
    float ar2 = 0.f, ai2 = 0.f;
    #pragma unroll
    for (int cc = 0; cc < 16; ++cc) {
        float2 t = t16[(cc*c) & 15];
        float xr = sR[cc*16 + d];
        ar2 = fmaf(xr, t.x, fmaf(-u, t.y, ar2));
        ai2 = fmaf(xr, t.y, fmaf( u, t.x, ai2));
    }
    long o = ((long)bh*256 + tid)*2;
    attn2[o]   = ar2 * (1.0f/16.0f);
    attn2[o+1] = ai2 * (1.0f/16.0f);
}

// ---------------------------------------------------------------------------
// Y[c][n] = sum_d attn2[c][d] * qf[d][n]   (complex)
__global__ void k_yf(const float* __restrict__ attn2, const float* __restrict__ Xr,
                     const float* __restrict__ Xi, float* __restrict__ Yr,
                     float* __restrict__ Yi) {
    int bh = blockIdx.x >> 6;
    int nb = blockIdx.x & 63;
    int tid = threadIdx.x;
    __shared__ float aR[256], aI[256];
    { long o = ((long)bh*256 + tid)*2; aR[tid] = attn2[o]; aI[tid] = attn2[o+1]; }
    __syncthreads();
    long n = (long)nb*256 + tid;
    long rowb = (long)bh*16;
    float qr[16], qi[16];
    #pragma unroll
    for (int dd = 0; dd < 16; ++dd) {
        qr[dd] = Xr[(rowb+dd)*P + n];
        qi[dd] = Xi[(rowb+dd)*P + n];
    }
    for (int cc = 0; cc < 16; ++cc) {
        float ar = 0.f, ai = 0.f;
        #pragma unroll
        for (int dd = 0; dd < 16; ++dd) {
            float tr = aR[cc*16+dd], ti = aI[cc*16+dd];
            ar = fmaf(tr, qr[dd], fmaf(-ti, qi[dd], ar));
            ai = fmaf(tr, qi[dd], fmaf( ti, qr[dd], ai));
        }
        Yr[(rowb+cc)*P + n] = ar;
        Yi[(rowb+cc)*P + n] = ai;
    }
}

// ---------------------------------------------------------------------------
// Fused q/k/v 1x1 convs: one block computes 8 out-ch for EACH of q,k,v from a
// single shared x read. Thread = 4 px (float4). The weight-delivery ratio is
// the bottleneck (6 b128 broadcasts per 96 fma); 4 px halves LDS-ops/fma vs
// the 2-px variant. __launch_bounds__(256,1) lets the allocator keep the 96
// acc floats in VGPRs (the R3 4-px attempt spilled to AGPR at default bounds).
__global__ __launch_bounds__(256, 1) void k_conv1x1qkv(
        const float* __restrict__ x,
        const float* __restrict__ Wq, const float* __restrict__ bq,
        const float* __restrict__ Wk, const float* __restrict__ bk,
        const float* __restrict__ Wv, const float* __restrict__ bv,
        float* __restrict__ Oq, float* __restrict__ Ok,
        float* __restrict__ Ov) {
    __shared__ float Wt[128][24];      // [c][0..7]=q, [8..15]=k, [16..23]=v
    __shared__ float bs[24];
    int g8 = blockIdx.y;               // 0..15 (8 out-ch per output)
    int b = blockIdx.z;
    int tid = threadIdx.x;
    for (int i = tid; i < 1024; i += 256) {
        int c = i >> 3, j = i & 7;
        Wt[c][j]      = Wq[(g8*8 + j)*128 + c];
        Wt[c][8 + j]  = Wk[(g8*8 + j)*128 + c];
        Wt[c][16 + j] = Wv[(g8*8 + j)*128 + c];
    }
    if (tid < 8) {
        bs[tid]      = bq[g8*8 + tid];
        bs[8 + tid]  = bk[g8*8 + tid];
        bs[16 + tid] = bv[g8*8 + tid];
    }
    __syncthreads();
    long pbase = (long)blockIdx.x*1024 + tid*4;
    const float4* xp = (const float4*)(x + (long)b*C*P + pbase);
    float4 aq[8], ak[8], av[8];
    #pragma unroll
    for (int j = 0; j < 8; ++j) {
        float v;
        v = bs[j];      aq[j] = make_float4(v, v, v, v);
        v = bs[8 + j];  ak[j] = make_float4(v, v, v, v);
        v = bs[16 + j]; av[j] = make_float4(v, v, v, v);
    }
    float4 xv = xp[0];
    for (int c = 0; c < 128; ++c) {
        float4 xn = xp[(c < 127 ? c + 1 : 127)*(P/4)];
        const float4* wp = (const float4*)(&Wt[c][0]);
        float4 wq0 = wp[0], wq1 = wp[1];
        float4 wk0 = wp[2], wk1 = wp[3];
        float4 wv0 = wp[4], wv1 = wp[5];
        FMA4(aq[0], wq0.x, xv) FMA4(aq[1], wq0.y, xv) FMA4(aq[2], wq0.z, xv) FMA4(aq[3], wq0.w, xv)
        FMA4(aq[4], wq1.x, xv) FMA4(aq[5], wq1.y, xv) FMA4(aq[6], wq1.z, xv) FMA4(aq[7], wq1.w, xv)
        FMA4(ak[0], wk0.x, xv) FMA4(ak[1], wk0.y, xv) FMA4(ak[2], wk0.z, xv) FMA4(ak[3], wk0.w, xv)
        FMA4(ak[4], wk1.x, xv) FMA4(ak[5], wk1.y, xv) FMA4(ak[6], wk1.z, xv) FMA4(ak[7], wk1.w, xv)
        FMA4(av[0], wv0.x, xv) FMA4(av[1], wv0.y, xv) FMA4(av[2], wv0.z, xv) FMA4(av[3], wv0.w, xv)
        FMA4(av[4], wv1.x, xv) FMA4(av[5], wv1.y, xv) FMA4(av[6], wv1.z, xv) FMA4(av[7], wv1.w, xv)
        xv = xn;
    }
    long ob = (long)b*C*P + (long)g8*8*P + pbase;
    #pragma unroll
    for (int j = 0; j < 8; ++j) {
        *(float4*)(Oq + ob + (long)j*P) = aq[j];
        *(float4*)(Ok + ob + (long)j*P) = ak[j];
        *(float4*)(Ov + ob + (long)j*P) = av[j];
    }
}

// ---------------------------------------------------------------------------
// Grouped conv, LDS-tiled; one block computes BOTH the 3x3 out-ch (g) and the
// 5x5 out-ch (64+g) from the shared 2-channel input tile. 16-row tiles.
__global__ __launch_bounds__(256) void k_gconv(
        const float* __restrict__ in, const float* __restrict__ w3,
        const float* __restrict__ w5, float* __restrict__ out) {
    __shared__ float S[2*20*132];
    __shared__ float ws3[18], ws5[50];
    int ht = blockIdx.x;       // 0..7
    int g  = blockIdx.y;       // 0..63
    int b  = blockIdx.z;
    int tid = threadIdx.x;
    int h0 = ht*16;
    const float* ib = in + ((long)b*C + 2*g)*P;
    if (tid < 18) ws3[tid] = w3[g*18 + tid];
    else if (tid < 68) ws5[tid-18] = w5[g*50 + tid - 18];
    for (int i = tid; i < 2*20*132; i += 256) {
        int ic = i / 2640, rem = i % 2640;
        int t = rem / 132, cc = rem % 132;
        int h = h0 - 2 + t, w = cc - 2;
        float v = 0.f;
        if (h >= 0 && h < 128 && w >= 0 && w < 128)
            v = ib[(long)ic*P + h*128 + w];
        S[i] = v;
    }
    __syncthreads();
    int w = tid & 127, rh = tid >> 7;
    int lr0 = rh*8;
    float acc3[8], acc5[8];
    #pragma unroll
    for (int r = 0; r < 8; ++r) { acc3[r] = 0.f; acc5[r] = 0.f; }
    #pragma unroll
    for (int ic = 0; ic < 2; ++ic) {
        const float* Sc = S + ic*2640;
        #pragma unroll
        for (int kx = 0; kx < 3; ++kx) {
            float col[10];
            #pragma unroll
            for (int i = 0; i < 10; ++i)
                col[i] = Sc[(lr0 + 1 + i)*132 + (w + 1 + kx)];
            #pragma unroll
            for (int ky = 0; ky < 3; ++ky) {
                float wv = ws3[ic*9 + ky*3 + kx];
                #pragma unroll
                for (int r = 0; r < 8; ++r)
                    acc3[r] = fmaf(wv, col[r + ky], acc3[r]);
            }
        }
        #pragma unroll
        for (int kx = 0; kx < 5; ++kx) {
            float col[12];
            #pragma unroll
            for (int i = 0; i < 12; ++i)
                col[i] = Sc[(lr0 + i)*132 + (w + kx)];
            #pragma unroll
            for (int ky = 0; ky < 5; ++ky) {
                float wv = ws5[ic*25 + ky*5 + kx];
                #pragma unroll
                for (int r = 0; r < 8; ++r)
                    acc5[r] = fmaf(wv, col[r + ky], acc5[r]);
            }
        }
    }
    long ob3 = ((long)b*C + g)*P;
    long ob5 = ((long)b*C + 64 + g)*P;
    #pragma unroll
    for (int r = 0; r < 8; ++r) {
        int h = h0 + lr0 + r;
        out[ob3 + h*128 + w] = acc3[r];
        out[ob5 + h*128 + w] = acc5[r];
    }
}

// ---------------------------------------------------------------------------
// attn_s: norm reciprocals from fused partials, then softmax.
__global__ void k_attn_s(const float* __restrict__ gramP, const float* __restrict__ qnormP,
                         const float* __restrict__ knormP, const float* __restrict__ temps,
                         float* __restrict__ attn) {
    int bh = blockIdx.x; int tid = threadIdx.x;
    int c = tid >> 4, d = tid & 15;
    __shared__ float sQ[16], sK[16];
    if (tid < 16) {
        float sq = 0.f, sk = 0.f;
        #pragma unroll
        for (int ck = 0; ck < 8; ++ck) {
            sq += qnormP[(long)(bh*8+ck)*16 + tid];
            sk += knormP[(long)(bh*8+ck)*16 + tid];
        }
        sQ[tid] = 1.0f / fmaxf(sqrtf(sq), 1e-12f);
        sK[tid] = 1.0f / fmaxf(sqrtf(sk), 1e-12f);
    }
    float g = 0.f;
    for (int ck = 0; ck < 8; ++ck) g += gramP[(long)(bh*8+ck)*256 + tid];
    __syncthreads();
    g *= sQ[c] * sK[d] * temps[bh & 7];
    float m = g;
    for (int off = 8; off >= 1; off >>= 1) m = fmaxf(m, __shfl_xor(m, off));
    float e = __expf(g - m);
    float s = e;
    for (int off = 8; off >= 1; off >>= 1) s += __shfl_xor(s, off);
    attn[(long)bh*256 + tid] = e / s;
}

__global__ void k_outs(const float* __restrict__ attn, const float* __restrict__ V,
                       float* __restrict__ out) {
    int bh = blockIdx.x >> 6, nb = blockIdx.x & 63;
    int tid = threadIdx.x;
    __shared__ float aS[256];
    aS[tid] = attn[(long)bh*256 + tid];
    __syncthreads();
    long n = (long)nb*256 + tid;
    long rowb = (long)bh*16;
    float vv[16];
    #pragma unroll
    for (int dd = 0; dd < 16; ++dd) vv[dd] = V[(rowb+dd)*P + n];
    for (int cc = 0; cc < 16; ++cc) {
        float a = 0.f;
        #pragma unroll
        for (int dd = 0; dd < 16; ++dd) a = fmaf(aS[cc*16+dd], vv[dd], a);
        out[(rowb+cc)*P + n] = a;
    }
}

// ---------------------------------------------------------------------------
// Projection with 2 stacked inputs. 16 out-ch per block, thread = 4 px
// (float4): 8 b128 broadcasts per 128 fma — rebalanced vs the 2-px/32-out
// variant (16 b128 : 128 fma, LDS-bound). Register prefetch of A/B;
// __launch_bounds__(256,1) to keep the 64-float acc in VGPRs.
// out = W[:, :128]*A + W[:, 128:]*Bc (+out if ADD)
template<bool ADD>
__global__ __launch_bounds__(256, 1) void k_proj2in(
        const float* __restrict__ A, const float* __restrict__ Bc,
        const float* __restrict__ W, float* __restrict__ out) {
    __shared__ float Wt[256][16];      // Wt[c][j] = W[(og*16+j)*256 + c], 16 KB
    int og = blockIdx.y;               // 0..7
    int b = blockIdx.z;
    int tid = threadIdx.x;
    for (int i = tid; i < 4096; i += 256) {
        int c = i >> 4, j = i & 15;
        Wt[c][j] = W[(og*16 + j)*256 + c];
    }
    __syncthreads();
    long pbase = (long)blockIdx.x*1024 + tid*4;
    long xb = (long)b*C*P;
    const float4* Ap = (const float4*)(A + xb + pbase);
    const float4* Bp = (const float4*)(Bc + xb + pbase);
    float4 acc[16];
    #pragma unroll
    for (int j = 0; j < 16; ++j) acc[j] = make_float4(0.f,0.f,0.f,0.f);
    float4 a = Ap[0], bb = Bp[0];
    for (int c = 0; c < 128; ++c) {
        int cn = (c < 127 ? c + 1 : 127);
        float4 an = Ap[cn*(P/4)];
        float4 bn = Bp[cn*(P/4)];
        const float4* w0p = (const float4*)(&Wt[c][0]);
        const float4* w1p = (const float4*)(&Wt[c + 128][0]);
        #pragma unroll
        for (int q = 0; q < 4; ++q) {
            float4 w0 = w0p[q], w1 = w1p[q];
            int j = q*4;
            acc[j+0].x = fmaf(w0.x, a.x, fmaf(w1.x, bb.x, acc[j+0].x));
            acc[j+0].y = fmaf(w0.x, a.y, fmaf(w1.x, bb.y, acc[j+0].y));
            acc[j+0].z = fmaf(w0.x, a.z, fmaf(w1.x, bb.z, acc[j+0].z));
            acc[j+0].w = fmaf(w0.x, a.w, fmaf(w1.x, bb.w, acc[j+0].w));
            acc[j+1].x = fmaf(w0.y, a.x, fmaf(w1.y, bb.x, acc[j+1].x));
            acc[j+1].y = fmaf(w0.y, a.y, fmaf(w1.y, bb.y, acc[j+1].y));
            acc[j+1].z = fmaf(w0.y, a.z, fmaf(w1.y, bb.z, acc[j+1].z));
            acc[j+1].w = fmaf(w0.y, a.w, fmaf(w1.y, bb.w, acc[j+1].w));
            acc[j+2].x = fmaf(w0.z, a.x, fmaf(w1.z, bb.x, acc[j+2].x));
            acc[j+2].y = fmaf(w0.z, a.y, fmaf(w1.z, bb.y, acc[j+2].y));
            acc[j+2].z = fmaf(w0.z, a.z, fmaf(w1.z, bb.z, acc[j+2].z));
            acc[j+2].w = fmaf(w0.z, a.w, fmaf(w1.z, bb.w, acc[j+2].w));
            acc[j+3].x = fmaf(w0.w, a.x, fmaf(w1.w, bb.x, acc[j+3].x));
            acc[j+3].y = fmaf(w0.w, a.y, fmaf(w1.w, bb.y, acc[j+3].y));
            acc[j+3].z = fmaf(w0.w, a.z, fmaf(w1.w, bb.z, acc[j+3].z));
            acc[j+3].w = fmaf(w0.w, a.w, fmaf(w1.w, bb.w, acc[j+3].w));
        }
        a = an; bb = bn;
    }
    float* op = out + xb + (long)og*16*P + pbase;
    #pragma unroll
    for (int j = 0; j < 16; ++j) {
        float4 v = acc[j];
        if (ADD) {
            float4 o = *(float4*)(op + (long)j*P);
            v.x += o.x; v.y += o.y; v.z += o.z; v.w += o.w;
        }
        *(float4*)(op + (long)j*P) = v;
    }
}

// ---------------------------------------------------------------------------
static long ws_need_bytes(int bc) {
    long pb = (long)bc * C * P;
    long extras = (long)bc*8*P           // Mg
                + (long)bc*1024*3        // normP, qnormP, knormP (8bh*8ck*16)
                + (long)bc*8*8*256       // gramC (real)
                + (long)bc*8*256*2       // attn2
                + (long)bc*8*8*256       // gramS
                + (long)bc*8*256;        // attnS
    return (5*pb + extras) * 4;
}

extern "C" void kernel_launch(void* const* d_in, const int* in_sizes, int n_in,
                              void* d_out, int out_size, void* d_ws, size_t ws_size,
                              hipStream_t stream) {
    const float* x      = (const float*)d_in[0];
    const float* temp_f = (const float*)d_in[1];
    const float* w1     = (const float*)d_in[2];
    const float* b1     = (const float*)d_in[3];
    const float* bng    = (const float*)d_in[4];
    const float* bnb    = (const float*)d_in[5];
    const float* bnm    = (const float*)d_in[6];
    const float* bnv    = (const float*)d_in[7];
    const float* w2     = (const float*)d_in[8];
    const float* b2     = (const float*)d_in[9];
    const float* projf  = (const float*)d_in[10];
    const float* temp_s = (const float*)d_in[11];
    const float* q1w = (const float*)d_in[12]; const float* q1b = (const float*)d_in[13];
    const float* k1w = (const float*)d_in[14]; const float* k1b = (const float*)d_in[15];
    const float* v1w = (const float*)d_in[16]; const float* v1b = (const float*)d_in[17];
    const float* q3w = (const float*)d_in[18]; const float* q5w = (const float*)d_in[19];
    const float* k3w = (const float*)d_in[20]; const float* k5w = (const float*)d_in[21];
    const float* v3w = (const float*)d_in[22]; const float* v5w = (const float*)d_in[23];
    const float* c3w = (const float*)d_in[24]; const float* c5w = (const float*)d_in[25];
    const float* projs  = (const float*)d_in[26];
    float* out = (float*)d_out;
    float* ws = (float*)d_ws;

    int bc = 1;
    if ((long)ws_size >= ws_need_bytes(8)) bc = 8;
    else if ((long)ws_size >= ws_need_bytes(4)) bc = 4;
    else if ((long)ws_size >= ws_need_bytes(2)) bc = 2;
    const int NB = bc;
    const long pb = (long)bc * C * P;

    float* t0 = ws + 0*pb;
    float* t1 = ws + 1*pb;
    float* t2 = ws + 2*pb;
    float* t3 = ws + 3*pb;
    float* t4 = ws + 4*pb;
    float* Mg    = ws + 5*pb;
    float* normF = Mg + (long)bc*8*P;       // bc*8bh*8ck*16 norm partials
    float* recQ  = normF + (long)bc*1024;
    float* recK  = recQ + (long)bc*1024;
    float* gramC = recK + (long)bc*1024;
    float* attn2 = gramC + (long)bc*8*8*256;
    float* gramS = attn2 + (long)bc*8*256*2;
    float* attnS = gramS + (long)bc*8*8*256;

    for (int ckk = 0; ckk < 8/bc; ++ckk) {
        const float* xc = x + (long)ckk * bc * C * P;
        float* outc = out + (long)ckk * bc * C * P;

        // ================= frequency branch =================
        k_fftrow<0><<<NB*C*32, 256, 0, stream>>>(xc, nullptr, t0, t1);      // rows fwd
        k_fftcol<-1,false><<<NB*C*4, 256, 0, stream>>>(t0, t1, nullptr, nullptr,
                                                       nullptr, t2, t3);    // XF=(t2,t3)
        k_gate_mid<<<NB*32, 256, 0, stream>>>(t2, w1, b1, bng, bnb, bnm, bnv, Mg);
        k_fftcol<1,true><<<NB*C*4, 256, 0, stream>>>(t2, t3, Mg, w2, b2,
                                                     t0, t1);               // gate h-IFFT
        k_fftrow<1><<<NB*C*32, 256, 0, stream>>>(t0, t1, t4, nullptr);      // OFL=t4
        k_gram_cr<<<NB*8*8, 256, 0, stream>>>(t2, t3, gramC, normF);        // gram+norm
        k_attn_f<<<NB*8, 256, 0, stream>>>(gramC, normF, temp_f, attn2);
        k_yf<<<NB*8*64, 256, 0, stream>>>(attn2, t2, t3, t0, t1);           // Y=(t0,t1)
        k_fftcol<1,false><<<NB*C*4, 256, 0, stream>>>(t0, t1, nullptr, nullptr,
                                                      nullptr, t2, t3);     // CT pass1
        k_fftrow<2><<<NB*C*32, 256, 0, stream>>>(t2, t3, t0, nullptr);      // OF=t0
        k_proj2in<false><<<dim3(16, 8, NB), 256, 0, stream>>>(t0, t4, projf, outc);

        // ================= spatial branch =================
        k_conv1x1qkv<<<dim3(16, 16, NB), 256, 0, stream>>>(xc, q1w, q1b, k1w, k1b,
                                                           v1w, v1b, t0, t1, t2);
        k_gconv<<<dim3(8, 64, NB), 256, 0, stream>>>(t0, q3w, q5w, t3);   // QS=t3
        k_gconv<<<dim3(8, 64, NB), 256, 0, stream>>>(t1, k3w, k5w, t4);   // KS=t4
        k_gconv<<<dim3(8, 64, NB), 256, 0, stream>>>(t2, v3w, v5w, t0);   // VS=t0
        k_gconv<<<dim3(8, 64, NB), 256, 0, stream>>>(xc, c3w, c5w, t1);   // OSL=t1
        k_gram_r<<<NB*8*8, 256, 0, stream>>>(t3, t4, gramS, recQ, recK);  // gram+norms
        k_attn_s<<<NB*8, 256, 0, stream>>>(gramS, recQ, recK, temp_s, attnS);
        k_outs<<<NB*8*64, 256, 0, stream>>>(attnS, t0, t2);         // OS=t2
        k_proj2in<true><<<dim3(16, 8, NB), 256, 0, stream>>>(t2, t1, projs, outc);
    }
}

// Round 8
// 1441.497 us; speedup vs baseline: 1.1739x; 1.0323x over previous
//
#include <hip/hip_runtime.h>
#include <math.h>

#define B 8
#define C 128
#define HEADS 8
#define HD 16
#define HH 128
#define WW 128
#define P 16384          // HH*WW

static __device__ __forceinline__ float PI2F() { return 6.28318530717958647692f; }

#define FMA4(ACC, W, X) \
    ACC.x = fmaf(W, X.x, ACC.x); ACC.y = fmaf(W, X.y, ACC.y); \
    ACC.z = fmaf(W, X.z, ACC.z); ACC.w = fmaf(W, X.w, ACC.w);

// ===========================================================================
// Radix-2 DIT FFT-128 along the STRIDED (h) axis. 32 columns per block,
// 256 threads. GATE variant fuses sigmoid(W2*Mg+b2)*XF into staging.
template<int SIGN, bool GATE>
__global__ __launch_bounds__(256) void k_fftcol(
        const float* __restrict__ inR, const float* __restrict__ inI,
        const float* __restrict__ Mg, const float* __restrict__ w2,
        const float* __restrict__ b2,
        float* __restrict__ outR, float* __restrict__ outI) {
    __shared__ float2 S[128*32];
    __shared__ float2 tw[64];
    int bid = blockIdx.x;
    int img = bid >> 2;
    int qo  = (bid & 3) * 32;
    int tid = threadIdx.x;
    if (tid < 64) {
        float a = PI2F() * (float)tid / 128.0f;
        float s_, c_; __sincosf(a, &s_, &c_);
        tw[tid] = make_float2(c_, SIGN > 0 ? s_ : -s_);
    }
    long base = (long)img * P;
    float w2r[8]; float b2c = 0.f;
    const float* mb = nullptr;
    if (GATE) {
        int c = img & 127;
        #pragma unroll
        for (int j = 0; j < 8; ++j) w2r[j] = w2[c*8 + j];
        b2c = b2[c];
        mb = Mg + (long)(img >> 7)*8*P;
    }
    #pragma unroll
    for (int t = 0; t < 16; ++t) {
        int idx = tid + t*256;
        int h = idx >> 5, cc = idx & 31;
        int off = h*128 + qo + cc;
        float xr = inR[base + off];
        float xi = inI[base + off];
        if (GATE) {
            float z = b2c;
            #pragma unroll
            for (int j = 0; j < 8; ++j) z = fmaf(w2r[j], mb[(long)j*P + off], z);
            float g = 1.0f / (1.0f + __expf(-z));
            xr *= g; xi *= g;
        }
        int hr = __brev(h) >> 25;          // 7-bit reversal
        S[hr*32 + cc] = make_float2(xr, xi);
    }
    __syncthreads();
    int ln = tid & 31, wid = tid >> 5;
    for (int s = 0; s < 7; ++s) {
        int half = 1 << s;
        #pragma unroll
        for (int q = 0; q < 8; ++q) {
            int j = wid*8 + q;
            int k = j & (half - 1);
            int g = j >> s;
            int i0 = (g << (s+1)) + k;
            int i1 = i0 + half;
            float2 u = S[i0*32 + ln];
            float2 v = S[i1*32 + ln];
            float2 w = tw[k << (6 - s)];
            float vr = v.x*w.x - v.y*w.y;
            float vi = v.x*w.y + v.y*w.x;
            S[i0*32 + ln] = make_float2(u.x + vr, u.y + vi);
            S[i1*32 + ln] = make_float2(u.x - vr, u.y - vi);
        }
        __syncthreads();
    }
    #pragma unroll
    for (int t = 0; t < 16; ++t) {
        int idx = tid + t*256;
        int k = idx >> 5, cc = idx & 31;
        float2 z = S[k*32 + cc];
        outR[base + k*128 + qo + cc] = z.x;
        outI[base + k*128 + qo + cc] = z.y;
    }
}

// ===========================================================================
// Radix-2 DIT FFT-128 along the CONTIGUOUS (w) axis. 4 rows/block, 256 thr.
// MODE 0: real fwd; MODE 1: inverse+abs/16384; MODE 2: CT pass2 (premul
// twiddle, inverse, abs, transposed float4 store).
template<int MODE>
__global__ __launch_bounds__(256) void k_fftrow(
        const float* __restrict__ inR, const float* __restrict__ inI,
        float* __restrict__ out, float* __restrict__ outI) {
    __shared__ float2 S[4*128];
    __shared__ float2 tw[64];
    int bid = blockIdx.x;
    int img = bid >> 5;
    int r0  = (bid & 31) * 4;
    int tid = threadIdx.x;
    if (tid < 64) {
        float a = PI2F() * (float)tid / 128.0f;
        float s_, c_; __sincosf(a, &s_, &c_);
        tw[tid] = make_float2(c_, MODE == 0 ? -s_ : s_);
    }
    long base = (long)img * P;
    #pragma unroll
    for (int t = 0; t < 2; ++t) {
        int idx = tid + t*256;
        int r = idx >> 7, w = idx & 127;
        long off = base + (long)(r0 + r)*128 + w;
        float xr = inR[off];
        float xi = (MODE == 0) ? 0.f : inI[off];
        if (MODE == 2) {
            int k2 = r0 + r;
            float ang = (PI2F()/16384.0f) * (float)(w * k2);
            float s_, c_; __sincosf(ang, &s_, &c_);
            float yr = xr*c_ - xi*s_;
            float yi = xr*s_ + xi*c_;
            xr = yr; xi = yi;
        }
        S[r*128 + (__brev(w) >> 25)] = make_float2(xr, xi);
    }
    __syncthreads();
    int r = tid >> 6, j = tid & 63;
    for (int s = 0; s < 7; ++s) {
        int half = 1 << s;
        int k = j & (half - 1);
        int g = j >> s;
        int i0 = (g << (s+1)) + k;
        int i1 = i0 + half;
        float2 u = S[r*128 + i0];
        float2 v = S[r*128 + i1];
        float2 w_ = tw[k << (6 - s)];
        float vr = v.x*w_.x - v.y*w_.y;
        float vi = v.x*w_.y + v.y*w_.x;
        S[r*128 + i0] = make_float2(u.x + vr, u.y + vi);
        S[r*128 + i1] = make_float2(u.x - vr, u.y - vi);
        __syncthreads();
    }
    if (MODE == 0) {
        #pragma unroll
        for (int t = 0; t < 2; ++t) {
            int idx = tid + t*256;
            int rr = idx >> 7, k = idx & 127;
            float2 z = S[rr*128 + k];
            long off = base + (long)(r0 + rr)*128 + k;
            out[off] = z.x; outI[off] = z.y;
        }
    } else if (MODE == 1) {
        #pragma unroll
        for (int t = 0; t < 2; ++t) {
            int idx = tid + t*256;
            int rr = idx >> 7, p = idx & 127;
            float2 z = S[rr*128 + p];
            out[base + (long)(r0 + rr)*128 + p] =
                sqrtf(z.x*z.x + z.y*z.y) * (1.0f/16384.0f);
        }
    } else {
        if (tid < 128) {
            int k1 = tid;
            float4 v;
            float2 z0 = S[0*128 + k1], z1 = S[1*128 + k1];
            float2 z2 = S[2*128 + k1], z3 = S[3*128 + k1];
            v.x = sqrtf(z0.x*z0.x + z0.y*z0.y) * (1.0f/16384.0f);
            v.y = sqrtf(z1.x*z1.x + z1.y*z1.y) * (1.0f/16384.0f);
            v.z = sqrtf(z2.x*z2.x + z2.y*z2.y) * (1.0f/16384.0f);
            v.w = sqrtf(z3.x*z3.x + z3.y*z3.y) * (1.0f/16384.0f);
            *(float4*)(out + base + (long)k1*128 + r0) = v;
        }
    }
}

// ---------------------------------------------------------------------------
// SE gate stage 1. 256 blocks (full CU coverage), float2 px, register
// prefetch, transposed weights in LDS (float4 broadcast reads).
__global__ __launch_bounds__(256) void k_gate_mid(
        const float* __restrict__ XFr, const float* __restrict__ w1,
        const float* __restrict__ b1, const float* __restrict__ gamma,
        const float* __restrict__ beta, const float* __restrict__ mean,
        const float* __restrict__ var, float* __restrict__ M) {
    __shared__ float Wt[128][8];
    int tid = threadIdx.x;
    for (int i = tid; i < 1024; i += 256) { int c = i >> 3, j = i & 7; Wt[c][j] = w1[j*128 + c]; }
    __syncthreads();
    int tile = blockIdx.x;             // NB*32
    int b = tile >> 5;
    long pbase = (long)(tile & 31)*512 + tid*2;
    const float2* xp = (const float2*)(XFr + (long)b*C*P + pbase);
    float2 acc[8];
    #pragma unroll
    for (int j = 0; j < 8; ++j) { float bj = b1[j]; acc[j] = make_float2(bj, bj); }
    float2 xv = xp[0];
    for (int c = 0; c < 128; ++c) {
        float2 xn = xp[(c < 127 ? c + 1 : 127)*(P/2)];
        const float4* wp = (const float4*)(&Wt[c][0]);
        float4 w0 = wp[0], w1_ = wp[1];
        acc[0].x = fmaf(w0.x, xv.x, acc[0].x); acc[0].y = fmaf(w0.x, xv.y, acc[0].y);
        acc[1].x = fmaf(w0.y, xv.x, acc[1].x); acc[1].y = fmaf(w0.y, xv.y, acc[1].y);
        acc[2].x = fmaf(w0.z, xv.x, acc[2].x); acc[2].y = fmaf(w0.z, xv.y, acc[2].y);
        acc[3].x = fmaf(w0.w, xv.x, acc[3].x); acc[3].y = fmaf(w0.w, xv.y, acc[3].y);
        acc[4].x = fmaf(w1_.x, xv.x, acc[4].x); acc[4].y = fmaf(w1_.x, xv.y, acc[4].y);
        acc[5].x = fmaf(w1_.y, xv.x, acc[5].x); acc[5].y = fmaf(w1_.y, xv.y, acc[5].y);
        acc[6].x = fmaf(w1_.z, xv.x, acc[6].x); acc[6].y = fmaf(w1_.z, xv.y, acc[6].y);
        acc[7].x = fmaf(w1_.w, xv.x, acc[7].x); acc[7].y = fmaf(w1_.w, xv.y, acc[7].y);
        xv = xn;
    }
    #pragma unroll
    for (int j = 0; j < 8; ++j) {
        float sc = rsqrtf(var[j] + 1e-5f) * gamma[j];
        float sh = beta[j] - mean[j]*sc;
        float2 v;
        v.x = fmaxf(fmaf(acc[j].x, sc, sh), 0.f);
        v.y = fmaxf(fmaf(acc[j].y, sc, sh), 0.f);
        *(float2*)(M + ((long)b*8 + j)*P + pbase) = v;
    }
}

// ---------------------------------------------------------------------------
// Complex Gram, REAL part only, LDS-tiled with fused row-norm partials.
__global__ __launch_bounds__(256) void k_gram_cr(
        const float* __restrict__ Xr, const float* __restrict__ Xi,
        float* __restrict__ gramP, float* __restrict__ normP) {
    __shared__ float Sr[16][260];
    __shared__ float Si[16][260];
    int bh = blockIdx.x >> 3, ck = blockIdx.x & 7;
    int tid = threadIdx.x;
    int tile = tid & 15;        // 4x4 tile id: ci = tile>>2, di = tile&3
    int slice = tid >> 4;       // n-slice 0..15
    int ci4 = (tile >> 2) * 4, di4 = (tile & 3) * 4;
    long rowb = (long)bh * 16;
    int n0 = ck * 2048;
    float acc[4][4];
    #pragma unroll
    for (int a = 0; a < 4; ++a)
        #pragma unroll
        for (int b2 = 0; b2 < 4; ++b2) acc[a][b2] = 0.f;
    float nacc = 0.f;
    int nrow = tid & 15;             // row for norm phase
    int ngrp = tid >> 4;             // 16 cols per group
    for (int sc = 0; sc < 8; ++sc) {
        int nb = n0 + sc*256;
        if (sc) __syncthreads();
        for (int i = tid; i < 1024; i += 256) {
            int r = i >> 6, col = (i & 63) * 4;
            *(float4*)(&Sr[r][col]) = *(const float4*)(Xr + (rowb + r)*P + nb + col);
            *(float4*)(&Si[r][col]) = *(const float4*)(Xi + (rowb + r)*P + nb + col);
        }
        __syncthreads();
        #pragma unroll
        for (int it0 = 0; it0 < 4; ++it0) {
            int it = (it0 + slice) & 3;          // rotation: slices hit distinct banks
            int n = slice*16 + it*4;
            float4 cr[4], cii[4], dr[4], dii[4];
            #pragma unroll
            for (int a = 0; a < 4; ++a) {
                cr[a]  = *(const float4*)(&Sr[ci4 + a][n]);
                cii[a] = *(const float4*)(&Si[ci4 + a][n]);
                dr[a]  = *(const float4*)(&Sr[di4 + a][n]);
                dii[a] = *(const float4*)(&Si[di4 + a][n]);
            }
            #pragma unroll
            for (int a = 0; a < 4; ++a)
                #pragma unroll
                for (int b2 = 0; b2 < 4; ++b2) {
                    float t = acc[a][b2];
                    t = fmaf(cr[a].x, dr[b2].x, fmaf(-cii[a].x, dii[b2].x, t));
                    t = fmaf(cr[a].y, dr[b2].y, fmaf(-cii[a].y, dii[b2].y, t));
                    t = fmaf(cr[a].z, dr[b2].z, fmaf(-cii[a].z, dii[b2].z, t));
                    t = fmaf(cr[a].w, dr[b2].w, fmaf(-cii[a].w, dii[b2].w, t));
                    acc[a][b2] = t;
                }
        }
        #pragma unroll
        for (int it0 = 0; it0 < 4; ++it0) {
            int it = (it0 + ngrp) & 3;
            int n = ngrp*16 + it*4;
            float4 r4 = *(const float4*)(&Sr[nrow][n]);
            float4 i4 = *(const float4*)(&Si[nrow][n]);
            nacc = fmaf(r4.x, r4.x, fmaf(i4.x, i4.x, nacc));
            nacc = fmaf(r4.y, r4.y, fmaf(i4.y, i4.y, nacc));
            nacc = fmaf(r4.z, r4.z, fmaf(i4.z, i4.z, nacc));
            nacc = fmaf(r4.w, r4.w, fmaf(i4.w, i4.w, nacc));
        }
    }
    __syncthreads();
    float* red  = &Sr[0][0];     // 16 tiles * 16 slices * 16 locals = 4096 floats
    float* redn = &Si[0][0];     // 16 rows * 16 groups
    #pragma unroll
    for (int a = 0; a < 4; ++a)
        #pragma unroll
        for (int b2 = 0; b2 < 4; ++b2)
            red[tile*256 + slice*16 + a*4 + b2] = acc[a][b2];
    redn[nrow*16 + ngrp] = nacc;
    __syncthreads();
    {
        int c = tid >> 4, d = tid & 15;
        int tI = (c >> 2)*4 + (d >> 2);
        int lo = (c & 3)*4 + (d & 3);
        float g = 0.f;
        #pragma unroll
        for (int s = 0; s < 16; ++s) g += red[tI*256 + s*16 + lo];
        gramP[(long)(bh*8 + ck)*256 + tid] = g;
    }
    if (tid < 16) {
        float s = 0.f;
        #pragma unroll
        for (int k = 0; k < 16; ++k) s += redn[tid*16 + k];
        normP[(long)(bh*8 + ck)*16 + tid] = s;
    }
}

// ---------------------------------------------------------------------------
// Real Gram, LDS-tiled, fused norm partials for BOTH Q (c-side) and K (d-side).
__global__ __launch_bounds__(256) void k_gram_r(
        const float* __restrict__ Q, const float* __restrict__ K,
        float* __restrict__ gramP, float* __restrict__ qnormP,
        float* __restrict__ knormP) {
    __shared__ float Sq[16][260];
    __shared__ float Sk[16][260];
    int bh = blockIdx.x >> 3, ck = blockIdx.x & 7;
    int tid = threadIdx.x;
    int tile = tid & 15;
    int slice = tid >> 4;
    int ci4 = (tile >> 2) * 4, di4 = (tile & 3) * 4;
    long rowb = (long)bh * 16;
    int n0 = ck * 2048;
    float acc[4][4];
    #pragma unroll
    for (int a = 0; a < 4; ++a)
        #pragma unroll
        for (int b2 = 0; b2 < 4; ++b2) acc[a][b2] = 0.f;
    float qacc = 0.f, kacc = 0.f;
    int nrow = tid & 15, ngrp = tid >> 4;
    for (int sc = 0; sc < 8; ++sc) {
        int nb = n0 + sc*256;
        if (sc) __syncthreads();
        for (int i = tid; i < 1024; i += 256) {
            int r = i >> 6, col = (i & 63) * 4;
            *(float4*)(&Sq[r][col]) = *(const float4*)(Q + (rowb + r)*P + nb + col);
            *(float4*)(&Sk[r][col]) = *(const float4*)(K + (rowb + r)*P + nb + col);
        }
        __syncthreads();
        #pragma unroll
        for (int it0 = 0; it0 < 4; ++it0) {
            int it = (it0 + slice) & 3;
            int n = slice*16 + it*4;
            float4 cq[4], dk[4];
            #pragma unroll
            for (int a = 0; a < 4; ++a) {
                cq[a] = *(const float4*)(&Sq[ci4 + a][n]);
                dk[a] = *(const float4*)(&Sk[di4 + a][n]);
            }
            #pragma unroll
            for (int a = 0; a < 4; ++a)
                #pragma unroll
                for (int b2 = 0; b2 < 4; ++b2) {
                    float t = acc[a][b2];
                    t = fmaf(cq[a].x, dk[b2].x, t);
                    t = fmaf(cq[a].y, dk[b2].y, t);
                    t = fmaf(cq[a].z, dk[b2].z, t);
                    t = fmaf(cq[a].w, dk[b2].w, t);
                    acc[a][b2] = t;
                }
        }
        #pragma unroll
        for (int it0 = 0; it0 < 4; ++it0) {
            int it = (it0 + ngrp) & 3;
            int n = ngrp*16 + it*4;
            float4 q4 = *(const float4*)(&Sq[nrow][n]);
            float4 k4 = *(const float4*)(&Sk[nrow][n]);
            qacc = fmaf(q4.x, q4.x, qacc); kacc = fmaf(k4.x, k4.x, kacc);
            qacc = fmaf(q4.y, q4.y, qacc); kacc = fmaf(k4.y, k4.y, kacc);
            qacc = fmaf(q4.z, q4.z, qacc); kacc = fmaf(k4.z, k4.z, kacc);
            qacc = fmaf(q4.w, q4.w, qacc); kacc = fmaf(k4.w, k4.w, kacc);
        }
    }
    __syncthreads();
    float* red  = &Sq[0][0];
    float* redn = &Sk[0][0];     // [0..255] = q partials, [256..511] = k partials
    #pragma unroll
    for (int a = 0; a < 4; ++a)
        #pragma unroll
        for (int b2 = 0; b2 < 4; ++b2)
            red[tile*256 + slice*16 + a*4 + b2] = acc[a][b2];
    redn[nrow*16 + ngrp] = qacc;
    redn[256 + nrow*16 + ngrp] = kacc;
    __syncthreads();
    {
        int c = tid >> 4, d = tid & 15;
        int tI = (c >> 2)*4 + (d >> 2);
        int lo = (c & 3)*4 + (d & 3);
        float g = 0.f;
        #pragma unroll
        for (int s = 0; s < 16; ++s) g += red[tI*256 + s*16 + lo];
        gramP[(long)(bh*8 + ck)*256 + tid] = g;
    }
    if (tid < 16) {
        float s = 0.f;
        #pragma unroll
        for (int k = 0; k < 16; ++k) s += redn[tid*16 + k];
        qnormP[(long)(bh*8 + ck)*16 + tid] = s;
    } else if (tid < 32) {
        int r = tid - 16;
        float s = 0.f;
        #pragma unroll
        for (int k = 0; k < 16; ++k) s += redn[256 + r*16 + k];
        knormP[(long)(bh*8 + ck)*16 + r] = s;
    }
}

// ---------------------------------------------------------------------------
// attn_f: real gram -> softmax; imag part exactly uniform 1/16; IDFT-16 over c.
__global__ void k_attn_f(const float* __restrict__ gramP, const float* __restrict__ normP,
                         const float* __restrict__ tempf, float* __restrict__ attn2) {
    int bh = blockIdx.x; int tid = threadIdx.x;
    int c = tid >> 4, d = tid & 15;
    int hh = bh & 7;
    __shared__ float sR[256];
    __shared__ float2 t16[16];
    __shared__ float sN[16];
    if (tid < 16) {
        float s = 0.f;
        #pragma unroll
        for (int ck = 0; ck < 8; ++ck) s += normP[(long)(bh*8+ck)*16 + tid];
        sN[tid] = 1.0f / fmaxf(sqrtf(s), 1e-12f);
        float a = PI2F() * (float)tid / 16.0f;
        t16[tid] = make_float2(__cosf(a), __sinf(a));
    }
    float gr = 0.f;
    for (int ck = 0; ck < 8; ++ck) gr += gramP[(long)(bh*8+ck)*256 + tid];
    __syncthreads();
    float vr = gr * sN[c] * sN[d] * tempf[hh];
    float mr = vr;
    for (int off = 8; off >= 1; off >>= 1) mr = fmaxf(mr, __shfl_xor(mr, off));
    float er = __expf(vr - mr);
    float ssr = er;
    for (int off = 8; off >= 1; off >>= 1) ssr += __shfl_xor(ssr, off);
    float arv = er / ssr;
    const float u = 1.0f/16.0f;
    sR[tid] = arv;
    __syncthreads();
    float ar2 = 0.f, ai2 = 0.f;
    #pragma unroll
    for (int cc = 0; cc < 16; ++cc) {
        float2 t = t16[(cc*c) & 15];
        float xr = sR[cc*16 + d];
        ar2 = fmaf(xr, t.x, fmaf(-u, t.y, ar2));
        ai2 = fmaf(xr, t.y, fmaf( u, t.x, ai2));
    }
    long o = ((long)bh*256 + tid)*2;
    attn2[o]   = ar2 * (1.0f/16.0f);
    attn2[o+1] = ai2 * (1.0f/16.0f);
}

// ---------------------------------------------------------------------------
// Y[c][n] = sum_d attn2[c][d] * qf[d][n]   (complex)
__global__ void k_yf(const float* __restrict__ attn2, const float* __restrict__ Xr,
                     const float* __restrict__ Xi, float* __restrict__ Yr,
                     float* __restrict__ Yi) {
    int bh = blockIdx.x >> 6;
    int nb = blockIdx.x & 63;
    int tid = threadIdx.x;
    __shared__ float aR[256], aI[256];
    { long o = ((long)bh*256 + tid)*2; aR[tid] = attn2[o]; aI[tid] = attn2[o+1]; }
    __syncthreads();
    long n = (long)nb*256 + tid;
    long rowb = (long)bh*16;
    float qr[16], qi[16];
    #pragma unroll
    for (int dd = 0; dd < 16; ++dd) {
        qr[dd] = Xr[(rowb+dd)*P + n];
        qi[dd] = Xi[(rowb+dd)*P + n];
    }
    for (int cc = 0; cc < 16; ++cc) {
        float ar = 0.f, ai = 0.f;
        #pragma unroll
        for (int dd = 0; dd < 16; ++dd) {
            float tr = aR[cc*16+dd], ti = aI[cc*16+dd];
            ar = fmaf(tr, qr[dd], fmaf(-ti, qi[dd], ar));
            ai = fmaf(tr, qi[dd], fmaf( ti, qr[dd], ai));
        }
        Yr[(rowb+cc)*P + n] = ar;
        Yi[(rowb+cc)*P + n] = ai;
    }
}

// ---------------------------------------------------------------------------
// q/k/v 1x1 convs, NON-FUSED (reverted): each block computes 16 out-ch of ONE
// of q/k/v. acc = 64 floats fits VGPRs — the fused 24-out variants all spilled
// to AGPR traffic and pinned at 157-162 us across 4 implementations (R3-R7).
// Transposed weights in LDS (4x ds_read_b128 broadcast per iter : 64 fma) +
// 1-deep x register prefetch. x read 3x is L3-absorbed (HBM at 9%).
__global__ __launch_bounds__(256) void k_conv1x1qkv(
        const float* __restrict__ x,
        const float* __restrict__ Wq, const float* __restrict__ bq,
        const float* __restrict__ Wk, const float* __restrict__ bk,
        const float* __restrict__ Wv, const float* __restrict__ bv,
        float* __restrict__ Oq, float* __restrict__ Ok,
        float* __restrict__ Ov) {
    __shared__ float Wt[128][16];
    __shared__ float bs[16];
    int og = blockIdx.y & 7, which = blockIdx.y >> 3;
    int b = blockIdx.z;
    const float* W    = which == 0 ? Wq : which == 1 ? Wk : Wv;
    const float* bias = which == 0 ? bq : which == 1 ? bk : bv;
    float* O          = which == 0 ? Oq : which == 1 ? Ok : Ov;
    int tid = threadIdx.x;
    for (int i = tid; i < 2048; i += 256) {
        int c = i >> 4, j = i & 15;
        Wt[c][j] = W[(og*16 + j)*128 + c];
    }
    if (tid < 16) bs[tid] = bias[og*16 + tid];
    __syncthreads();
    long pbase = (long)blockIdx.x*1024 + tid*4;
    const float4* xp = (const float4*)(x + (long)b*C*P + pbase);
    float4 acc[16];
    #pragma unroll
    for (int j = 0; j < 16; ++j) { float bj = bs[j]; acc[j] = make_float4(bj,bj,bj,bj); }
    float4 xv = xp[0];
    for (int c = 0; c < 128; ++c) {
        float4 xn = xp[(c < 127 ? c + 1 : 127)*(P/4)];
        const float4* wp = (const float4*)(&Wt[c][0]);
        float4 w0 = wp[0], w1 = wp[1], w2 = wp[2], w3 = wp[3];
        FMA4(acc[ 0], w0.x, xv) FMA4(acc[ 1], w0.y, xv) FMA4(acc[ 2], w0.z, xv) FMA4(acc[ 3], w0.w, xv)
        FMA4(acc[ 4], w1.x, xv) FMA4(acc[ 5], w1.y, xv) FMA4(acc[ 6], w1.z, xv) FMA4(acc[ 7], w1.w, xv)
        FMA4(acc[ 8], w2.x, xv) FMA4(acc[ 9], w2.y, xv) FMA4(acc[10], w2.z, xv) FMA4(acc[11], w2.w, xv)
        FMA4(acc[12], w3.x, xv) FMA4(acc[13], w3.y, xv) FMA4(acc[14], w3.z, xv) FMA4(acc[15], w3.w, xv)
        xv = xn;
    }
    float* op = O + (long)b*C*P + (long)og*16*P + pbase;
    #pragma unroll
    for (int j = 0; j < 16; ++j) *(float4*)(op + (long)j*P) = acc[j];
}

// ---------------------------------------------------------------------------
// Grouped conv, LDS-tiled; one block computes BOTH the 3x3 out-ch (g) and the
// 5x5 out-ch (64+g) from the shared 2-channel input tile. 16-row tiles.
__global__ __launch_bounds__(256) void k_gconv(
        const float* __restrict__ in, const float* __restrict__ w3,
        const float* __restrict__ w5, float* __restrict__ out) {
    __shared__ float S[2*20*132];
    __shared__ float ws3[18], ws5[50];
    int ht = blockIdx.x;       // 0..7
    int g  = blockIdx.y;       // 0..63
    int b  = blockIdx.z;
    int tid = threadIdx.x;
    int h0 = ht*16;
    const float* ib = in + ((long)b*C + 2*g)*P;
    if (tid < 18) ws3[tid] = w3[g*18 + tid];
    else if (tid < 68) ws5[tid-18] = w5[g*50 + tid - 18];
    for (int i = tid; i < 2*20*132; i += 256) {
        int ic = i / 2640, rem = i % 2640;
        int t = rem / 132, cc = rem % 132;
        int h = h0 - 2 + t, w = cc - 2;
        float v = 0.f;
        if (h >= 0 && h < 128 && w >= 0 && w < 128)
            v = ib[(long)ic*P + h*128 + w];
        S[i] = v;
    }
    __syncthreads();
    int w = tid & 127, rh = tid >> 7;
    int lr0 = rh*8;
    float acc3[8], acc5[8];
    #pragma unroll
    for (int r = 0; r < 8; ++r) { acc3[r] = 0.f; acc5[r] = 0.f; }
    #pragma unroll
    for (int ic = 0; ic < 2; ++ic) {
        const float* Sc = S + ic*2640;
        #pragma unroll
        for (int kx = 0; kx < 3; ++kx) {
            float col[10];
            #pragma unroll
            for (int i = 0; i < 10; ++i)
                col[i] = Sc[(lr0 + 1 + i)*132 + (w + 1 + kx)];
            #pragma unroll
            for (int ky = 0; ky < 3; ++ky) {
                float wv = ws3[ic*9 + ky*3 + kx];
                #pragma unroll
                for (int r = 0; r < 8; ++r)
                    acc3[r] = fmaf(wv, col[r + ky], acc3[r]);
            }
        }
        #pragma unroll
        for (int kx = 0; kx < 5; ++kx) {
            float col[12];
            #pragma unroll
            for (int i = 0; i < 12; ++i)
                col[i] = Sc[(lr0 + i)*132 + (w + kx)];
            #pragma unroll
            for (int ky = 0; ky < 5; ++ky) {
                float wv = ws5[ic*25 + ky*5 + kx];
                #pragma unroll
                for (int r = 0; r < 8; ++r)
                    acc5[r] = fmaf(wv, col[r + ky], acc5[r]);
            }
        }
    }
    long ob3 = ((long)b*C + g)*P;
    long ob5 = ((long)b*C + 64 + g)*P;
    #pragma unroll
    for (int r = 0; r < 8; ++r) {
        int h = h0 + lr0 + r;
        out[ob3 + h*128 + w] = acc3[r];
        out[ob5 + h*128 + w] = acc5[r];
    }
}

// ---------------------------------------------------------------------------
// attn_s: norm reciprocals from fused partials, then softmax.
__global__ void k_attn_s(const float* __restrict__ gramP, const float* __restrict__ qnormP,
                         const float* __restrict__ knormP, const float* __restrict__ temps,
                         float* __restrict__ attn) {
    int bh = blockIdx.x; int tid = threadIdx.x;
    int c = tid >> 4, d = tid & 15;
    __shared__ float sQ[16], sK[16];
    if (tid < 16) {
        float sq = 0.f, sk = 0.f;
        #pragma unroll
        for (int ck = 0; ck < 8; ++ck) {
            sq += qnormP[(long)(bh*8+ck)*16 + tid];
            sk += knormP[(long)(bh*8+ck)*16 + tid];
        }
        sQ[tid] = 1.0f / fmaxf(sqrtf(sq), 1e-12f);
        sK[tid] = 1.0f / fmaxf(sqrtf(sk), 1e-12f);
    }
    float g = 0.f;
    for (int ck = 0; ck < 8; ++ck) g += gramP[(long)(bh*8+ck)*256 + tid];
    __syncthreads();
    g *= sQ[c] * sK[d] * temps[bh & 7];
    float m = g;
    for (int off = 8; off >= 1; off >>= 1) m = fmaxf(m, __shfl_xor(m, off));
    float e = __expf(g - m);
    float s = e;
    for (int off = 8; off >= 1; off >>= 1) s += __shfl_xor(s, off);
    attn[(long)bh*256 + tid] = e / s;
}

__global__ void k_outs(const float* __restrict__ attn, const float* __restrict__ V,
                       float* __restrict__ out) {
    int bh = blockIdx.x >> 6, nb = blockIdx.x & 63;
    int tid = threadIdx.x;
    __shared__ float aS[256];
    aS[tid] = attn[(long)bh*256 + tid];
    __syncthreads();
    long n = (long)nb*256 + tid;
    long rowb = (long)bh*16;
    float vv[16];
    #pragma unroll
    for (int dd = 0; dd < 16; ++dd) vv[dd] = V[(rowb+dd)*P + n];
    for (int cc = 0; cc < 16; ++cc) {
        float a = 0.f;
        #pragma unroll
        for (int dd = 0; dd < 16; ++dd) a = fmaf(aS[cc*16+dd], vv[dd], a);
        out[(rowb+cc)*P + n] = a;
    }
}

// ---------------------------------------------------------------------------
// Projection with 2 stacked inputs. 16 out-ch per block, thread = 4 px
// (float4): 8 b128 broadcasts per 128 fma. Register prefetch of A/B;
// __launch_bounds__(256,1) to keep the 64-float acc in VGPRs.
// out = W[:, :128]*A + W[:, 128:]*Bc (+out if ADD)
template<bool ADD>
__global__ __launch_bounds__(256, 1) void k_proj2in(
        const float* __restrict__ A, const float* __restrict__ Bc,
        const float* __restrict__ W, float* __restrict__ out) {
    __shared__ float Wt[256][16];      // Wt[c][j] = W[(og*16+j)*256 + c], 16 KB
    int og = blockIdx.y;               // 0..7
    int b = blockIdx.z;
    int tid = threadIdx.x;
    for (int i = tid; i < 4096; i += 256) {
        int c = i >> 4, j = i & 15;
        Wt[c][j] = W[(og*16 + j)*256 + c];
    }
    __syncthreads();
    long pbase = (long)blockIdx.x*1024 + tid*4;
    long xb = (long)b*C*P;
    const float4* Ap = (const float4*)(A + xb + pbase);
    const float4* Bp = (const float4*)(Bc + xb + pbase);
    float4 acc[16];
    #pragma unroll
    for (int j = 0; j < 16; ++j) acc[j] = make_float4(0.f,0.f,0.f,0.f);
    float4 a = Ap[0], bb = Bp[0];
    for (int c = 0; c < 128; ++c) {
        int cn = (c < 127 ? c + 1 : 127);
        float4 an = Ap[cn*(P/4)];
        float4 bn = Bp[cn*(P/4)];
        const float4* w0p = (const float4*)(&Wt[c][0]);
        const float4* w1p = (const float4*)(&Wt[c + 128][0]);
        #pragma unroll
        for (int q = 0; q < 4; ++q) {
            float4 w0 = w0p[q], w1 = w1p[q];
            int j = q*4;
            acc[j+0].x = fmaf(w0.x, a.x, fmaf(w1.x, bb.x, acc[j+0].x));
            acc[j+0].y = fmaf(w0.x, a.y, fmaf(w1.x, bb.y, acc[j+0].y));
            acc[j+0].z = fmaf(w0.x, a.z, fmaf(w1.x, bb.z, acc[j+0].z));
            acc[j+0].w = fmaf(w0.x, a.w, fmaf(w1.x, bb.w, acc[j+0].w));
            acc[j+1].x = fmaf(w0.y, a.x, fmaf(w1.y, bb.x, acc[j+1].x));
            acc[j+1].y = fmaf(w0.y, a.y, fmaf(w1.y, bb.y, acc[j+1].y));
            acc[j+1].z = fmaf(w0.y, a.z, fmaf(w1.y, bb.z, acc[j+1].z));
            acc[j+1].w = fmaf(w0.y, a.w, fmaf(w1.y, bb.w, acc[j+1].w));
            acc[j+2].x = fmaf(w0.z, a.x, fmaf(w1.z, bb.x, acc[j+2].x));
            acc[j+2].y = fmaf(w0.z, a.y, fmaf(w1.z, bb.y, acc[j+2].y));
            acc[j+2].z = fmaf(w0.z, a.z, fmaf(w1.z, bb.z, acc[j+2].z));
            acc[j+2].w = fmaf(w0.z, a.w, fmaf(w1.z, bb.w, acc[j+2].w));
            acc[j+3].x = fmaf(w0.w, a.x, fmaf(w1.w, bb.x, acc[j+3].x));
            acc[j+3].y = fmaf(w0.w, a.y, fmaf(w1.w, bb.y, acc[j+3].y));
            acc[j+3].z = fmaf(w0.w, a.z, fmaf(w1.w, bb.z, acc[j+3].z));
            acc[j+3].w = fmaf(w0.w, a.w, fmaf(w1.w, bb.w, acc[j+3].w));
        }
        a = an; bb = bn;
    }
    float* op = out + xb + (long)og*16*P + pbase;
    #pragma unroll
    for (int j = 0; j < 16; ++j) {
        float4 v = acc[j];
        if (ADD) {
            float4 o = *(float4*)(op + (long)j*P);
            v.x += o.x; v.y += o.y; v.z += o.z; v.w += o.w;
        }
        *(float4*)(op + (long)j*P) = v;
    }
}

// ---------------------------------------------------------------------------
static long ws_need_bytes(int bc) {
    long pb = (long)bc * C * P;
    long extras = (long)bc*8*P           // Mg
                + (long)bc*1024*3        // normP, qnormP, knormP (8bh*8ck*16)
                + (long)bc*8*8*256       // gramC (real)
                + (long)bc*8*256*2       // attn2
                + (long)bc*8*8*256       // gramS
                + (long)bc*8*256;        // attnS
    return (5*pb + extras) * 4;
}

extern "C" void kernel_launch(void* const* d_in, const int* in_sizes, int n_in,
                              void* d_out, int out_size, void* d_ws, size_t ws_size,
                              hipStream_t stream) {
    const float* x      = (const float*)d_in[0];
    const float* temp_f = (const float*)d_in[1];
    const float* w1     = (const float*)d_in[2];
    const float* b1     = (const float*)d_in[3];
    const float* bng    = (const float*)d_in[4];
    const float* bnb    = (const float*)d_in[5];
    const float* bnm    = (const float*)d_in[6];
    const float* bnv    = (const float*)d_in[7];
    const float* w2     = (const float*)d_in[8];
    const float* b2     = (const float*)d_in[9];
    const float* projf  = (const float*)d_in[10];
    const float* temp_s = (const float*)d_in[11];
    const float* q1w = (const float*)d_in[12]; const float* q1b = (const float*)d_in[13];
    const float* k1w = (const float*)d_in[14]; const float* k1b = (const float*)d_in[15];
    const float* v1w = (const float*)d_in[16]; const float* v1b = (const float*)d_in[17];
    const float* q3w = (const float*)d_in[18]; const float* q5w = (const float*)d_in[19];
    const float* k3w = (const float*)d_in[20]; const float* k5w = (const float*)d_in[21];
    const float* v3w = (const float*)d_in[22]; const float* v5w = (const float*)d_in[23];
    const float* c3w = (const float*)d_in[24]; const float* c5w = (const float*)d_in[25];
    const float* projs  = (const float*)d_in[26];
    float* out = (float*)d_out;
    float* ws = (float*)d_ws;

    int bc = 1;
    if ((long)ws_size >= ws_need_bytes(8)) bc = 8;
    else if ((long)ws_size >= ws_need_bytes(4)) bc = 4;
    else if ((long)ws_size >= ws_need_bytes(2)) bc = 2;
    const int NB = bc;
    const long pb = (long)bc * C * P;

    float* t0 = ws + 0*pb;
    float* t1 = ws + 1*pb;
    float* t2 = ws + 2*pb;
    float* t3 = ws + 3*pb;
    float* t4 = ws + 4*pb;
    float* Mg    = ws + 5*pb;
    float* normF = Mg + (long)bc*8*P;       // bc*8bh*8ck*16 norm partials
    float* recQ  = normF + (long)bc*1024;
    float* recK  = recQ + (long)bc*1024;
    float* gramC = recK + (long)bc*1024;
    float* attn2 = gramC + (long)bc*8*8*256;
    float* gramS = attn2 + (long)bc*8*256*2;
    float* attnS = gramS + (long)bc*8*8*256;

    for (int ckk = 0; ckk < 8/bc; ++ckk) {
        const float* xc = x + (long)ckk * bc * C * P;
        float* outc = out + (long)ckk * bc * C * P;

        // ================= frequency branch =================
        k_fftrow<0><<<NB*C*32, 256, 0, stream>>>(xc, nullptr, t0, t1);      // rows fwd
        k_fftcol<-1,false><<<NB*C*4, 256, 0, stream>>>(t0, t1, nullptr, nullptr,
                                                       nullptr, t2, t3);    // XF=(t2,t3)
        k_gate_mid<<<NB*32, 256, 0, stream>>>(t2, w1, b1, bng, bnb, bnm, bnv, Mg);
        k_fftcol<1,true><<<NB*C*4, 256, 0, stream>>>(t2, t3, Mg, w2, b2,
                                                     t0, t1);               // gate h-IFFT
        k_fftrow<1><<<NB*C*32, 256, 0, stream>>>(t0, t1, t4, nullptr);      // OFL=t4
        k_gram_cr<<<NB*8*8, 256, 0, stream>>>(t2, t3, gramC, normF);        // gram+norm
        k_attn_f<<<NB*8, 256, 0, stream>>>(gramC, normF, temp_f, attn2);
        k_yf<<<NB*8*64, 256, 0, stream>>>(attn2, t2, t3, t0, t1);           // Y=(t0,t1)
        k_fftcol<1,false><<<NB*C*4, 256, 0, stream>>>(t0, t1, nullptr, nullptr,
                                                      nullptr, t2, t3);     // CT pass1
        k_fftrow<2><<<NB*C*32, 256, 0, stream>>>(t2, t3, t0, nullptr);      // OF=t0
        k_proj2in<false><<<dim3(16, 8, NB), 256, 0, stream>>>(t0, t4, projf, outc);

        // ================= spatial branch =================
        k_conv1x1qkv<<<dim3(16, 24, NB), 256, 0, stream>>>(xc, q1w, q1b, k1w, k1b,
                                                           v1w, v1b, t0, t1, t2);
        k_gconv<<<dim3(8, 64, NB), 256, 0, stream>>>(t0, q3w, q5w, t3);   // QS=t3
        k_gconv<<<dim3(8, 64, NB), 256, 0, stream>>>(t1, k3w, k5w, t4);   // KS=t4
        k_gconv<<<dim3(8, 64, NB), 256, 0, stream>>>(t2, v3w, v5w, t0);   // VS=t0
        k_gconv<<<dim3(8, 64, NB), 256, 0, stream>>>(xc, c3w, c5w, t1);   // OSL=t1
        k_gram_r<<<NB*8*8, 256, 0, stream>>>(t3, t4, gramS, recQ, recK);  // gram+norms
        k_attn_s<<<NB*8, 256, 0, stream>>>(gramS, recQ, recK, temp_s, attnS);
        k_outs<<<NB*8*64, 256, 0, stream>>>(attnS, t0, t2);         // OS=t2
        k_proj2in<true><<<dim3(16, 8, NB), 256, 0, stream>>>(t2, t1, projs, outc);
    }
}